// Round 6
// baseline (728.169 us; speedup 1.0000x reference)
//
#include <hip/hip_runtime.h>
#include <hip/hip_bf16.h>

typedef __hip_bfloat16 bf16;
using f32x4  = __attribute__((ext_vector_type(4))) float;
using short8 = __attribute__((ext_vector_type(8))) short;

// B=8, T=12, N=325, K=8 heads, d=64, D=512, BT=96, M=31200
#define M_ROWS   31200
#define N_TOK    325
#define D_MODEL  512
#define QKV_LD   1536

// ---------------------------------------------------------------------------
// dtype detection: device inputs are either f32 or bf16 (flag=1 -> f32).
__global__ void init_flag(int* flag) { if (threadIdx.x == 0) *flag = 0; }

__global__ void detect_dtype(const unsigned short* __restrict__ x, int* flag)
{
    int i = blockIdx.x * 256 + threadIdx.x;   // 64 blocks * 256 = 16384 halves
    unsigned short h = x[i];
    int e = (h >> 7) & 0xFF;
    if (e >= 135) atomicOr(flag, 1);
}

__device__ __forceinline__ float load_in(const void* p, size_t i, bool f32)
{
    return f32 ? ((const float*)p)[i] : __bfloat162float(((const bf16*)p)[i]);
}

// ---------------------------------------------------------------------------
// tiled transpose: src [krows][ncols] -> dst [ncols][krows] bf16 (coalesced)
__global__ void transpose_w_tiled(const void* __restrict__ src, bf16* __restrict__ dst,
                                  int krows, int ncols, const int* __restrict__ flag)
{
    __shared__ float tile[32][33];
    const bool f32 = (*flag != 0);
    const int kt = blockIdx.y * 32, nt = blockIdx.x * 32;
    const int tx = threadIdx.x & 31, ty = threadIdx.x >> 5;   // 32 x 8
#pragma unroll
    for (int r = 0; r < 32; r += 8)
        tile[ty + r][tx] = load_in(src, (size_t)(kt + ty + r) * ncols + (nt + tx), f32);
    __syncthreads();
#pragma unroll
    for (int r = 0; r < 32; r += 8)
        dst[(size_t)(nt + ty + r) * krows + (kt + tx)] = __float2bfloat16(tile[tx][ty + r]);
}

__global__ void prep_bias(const void* __restrict__ bq, const void* __restrict__ bk,
                          const void* __restrict__ bv, const void* __restrict__ b1,
                          const void* __restrict__ b2,
                          float* __restrict__ biasQKV, float* __restrict__ b1f,
                          float* __restrict__ b2f, const int* __restrict__ flag)
{
    const bool f32 = (*flag != 0);
    int i = blockIdx.x * 256 + threadIdx.x;
    if (i < 512) {
        biasQKV[i]        = load_in(bq, i, f32);
        biasQKV[512 + i]  = load_in(bk, i, f32);
        biasQKV[1024 + i] = load_in(bv, i, f32);
        b1f[i] = load_in(b1, i, f32);
        b2f[i] = load_in(b2, i, f32);
    }
}

// ---------------------------------------------------------------------------
// 128x128-tile bf16-MFMA GEMM (verified round-4 baseline, unchanged)
template<int AMODE, int OUTF32>
__global__ __launch_bounds__(256) void gemm_bt(
    const void* __restrict__ A0v, const void* __restrict__ A1v, int ksplit, int lda,
    const bf16* __restrict__ Bt, const float* __restrict__ bias,
    void* __restrict__ Cv, int M, int Kdim, int ldc, int do_relu,
    const int* __restrict__ flag)
{
    __shared__ alignas(16) bf16 As[128 * 40];
    __shared__ alignas(16) bf16 Bs[128 * 40];
    const bool af32 = (AMODE == 1) && (*flag != 0);
    const int t    = threadIdx.x;
    const int m0   = blockIdx.x * 128;
    const int n0   = blockIdx.y * 128;
    const int wave = t >> 6, lane = t & 63;
    const int wm   = (wave >> 1) * 64, wn = (wave & 1) * 64;
    const int lrow = lane & 15, lk8 = (lane >> 4) * 8;
    f32x4 acc[4][4] = {};
    const int nk = Kdim >> 5;

    for (int ks = 0; ks < nk; ++ks) {
        const int kk = ks << 5;
#pragma unroll
        for (int i = 0; i < 2; ++i) {
            int idx = t + i * 256;
            int ar  = idx >> 2, ac = (idx & 3) << 3;
            int gk  = kk + ac;
            int grow = m0 + ar;
            short8 va = {0, 0, 0, 0, 0, 0, 0, 0};
            if (grow < M) {
                const bool lo = (gk < ksplit);
                const void* base = lo ? A0v : A1v;
                size_t off = (size_t)grow * lda + (lo ? gk : (gk - ksplit));
                if (af32) {
                    const float* s = (const float*)base + off;
#pragma unroll
                    for (int j = 0; j < 8; ++j)
                        ((bf16*)&va)[j] = __float2bfloat16(s[j]);
                } else {
                    va = *(const short8*)((const bf16*)base + off);
                }
            }
            *(short8*)&As[ar * 40 + ac] = va;
            *(uint4*)&Bs[ar * 40 + ac] =
                *(const uint4*)(Bt + (size_t)(n0 + ar) * Kdim + gk);
        }
        __syncthreads();
        short8 af[4], bfr[4];
#pragma unroll
        for (int i = 0; i < 4; ++i) {
            af[i]  = *(const short8*)&As[(wm + i * 16 + lrow) * 40 + lk8];
            bfr[i] = *(const short8*)&Bs[(wn + i * 16 + lrow) * 40 + lk8];
        }
#pragma unroll
        for (int i = 0; i < 4; ++i)
#pragma unroll
            for (int j = 0; j < 4; ++j)
                acc[i][j] = __builtin_amdgcn_mfma_f32_16x16x32_bf16(
                    af[i], bfr[j], acc[i][j], 0, 0, 0);
        __syncthreads();
    }

    const int r4 = (lane >> 4) * 4;
#pragma unroll
    for (int i = 0; i < 4; ++i) {
#pragma unroll
        for (int r = 0; r < 4; ++r) {
            int grow = m0 + wm + i * 16 + r4 + r;
            if (grow >= M) continue;
#pragma unroll
            for (int j = 0; j < 4; ++j) {
                int gcol = n0 + wn + j * 16 + lrow;
                float v  = acc[i][j][r] + bias[gcol];
                if (do_relu) v = fmaxf(v, 0.0f);
                if (OUTF32)
                    ((float*)Cv)[(size_t)grow * ldc + gcol] = v;
                else
                    ((bf16*)Cv)[(size_t)grow * ldc + gcol] = __float2bfloat16(v);
            }
        }
    }
}

// ---------------------------------------------------------------------------
// Attention v2.1: one block per (bt, h). 256 threads, 4 waves.
// K resident [336][72] (zero-padded rows >=325); V resident TRANSPOSED
// [64][354] so PV B-fragments are contiguous short8 reads. ~126 KiB LDS,
// 1 block/CU. Loop over 21 row-tiles of 16 q-rows.
// FIX vs v2: PA_LD 338 -> 360. Softmax zero-pads pa cols up to 351; with
// PA_LD=338 rows overlapped (row r cols 338..351 clobbered row r+1 cols
// 0..13) -> corrupted P -> wrong ctx/out (round-5 absmax 0.25).
#define KS_LD  72
#define VT_LD  354
#define SC_LD  337
#define PA_LD  360
__global__ __launch_bounds__(256) void attn_kernel(
    bf16* __restrict__ qkv, float* __restrict__ attn_out)
{
    __shared__ alignas(16) bf16  Ks[336 * KS_LD];
    __shared__ alignas(16) bf16  Vt[64 * VT_LD + 32];
    __shared__ alignas(16) bf16  qs[16 * KS_LD];
    __shared__ alignas(16) float sc[16 * SC_LD];
    __shared__ alignas(16) bf16  pa[16 * PA_LD];
    const int t = threadIdx.x, lane = t & 63, wave = t >> 6;
    const int h = blockIdx.x & 7, bt = blockIdx.x >> 3;
    const size_t rowbase = (size_t)bt * N_TOK;
    const int lrow = lane & 15, lk8 = (lane >> 4) * 8;
    const int r4 = (lane >> 4) * 4;

    // ---- stage K (rows 0..335, zero-padded)
    for (int task = t; task < 336 * 8; task += 256) {
        int m = task >> 3, e0 = (task & 7) << 3;
        short8 v = {0, 0, 0, 0, 0, 0, 0, 0};
        if (m < N_TOK)
            v = *(const short8*)(qkv + (rowbase + m) * QKV_LD + 512 + h * 64 + e0);
        *(short8*)&Ks[m * KS_LD + e0] = v;
    }
    // ---- stage V transposed (cols 0..351, zero-padded)
    for (int task = t; task < 352 * 8; task += 256) {
        int m = task >> 3, e0 = (task & 7) << 3;
        short8 v = {0, 0, 0, 0, 0, 0, 0, 0};
        if (m < N_TOK)
            v = *(const short8*)(qkv + (rowbase + m) * QKV_LD + 1024 + h * 64 + e0);
#pragma unroll
        for (int j = 0; j < 8; ++j)
            Vt[(e0 + j) * VT_LD + m] = ((bf16*)&v)[j];
    }

    for (int rt = 0; rt < 21; ++rt) {
        const int r0 = rt * 16;
        __syncthreads();
        // stage Q tile (16 rows x 64)
        if (t < 128) {
            int rr = t >> 3, e0 = (t & 7) << 3;
            int n  = r0 + rr;
            short8 v = {0, 0, 0, 0, 0, 0, 0, 0};
            if (n < N_TOK)
                v = *(const short8*)(qkv + (rowbase + n) * QKV_LD + h * 64 + e0);
            *(short8*)&qs[rr * KS_LD + e0] = v;
        }
        __syncthreads();

        // ---- QK^T: col-tiles ct = wave, wave+4, ... <= rt
        for (int ct = wave; ct <= rt; ct += 4) {
            f32x4 a = {0.f, 0.f, 0.f, 0.f};
#pragma unroll
            for (int ks2 = 0; ks2 < 2; ++ks2) {
                short8 qa = *(const short8*)&qs[lrow * KS_LD + ks2 * 32 + lk8];
                short8 kb = *(const short8*)&Ks[(ct * 16 + lrow) * KS_LD + ks2 * 32 + lk8];
                a = __builtin_amdgcn_mfma_f32_16x16x32_bf16(qa, kb, a, 0, 0, 0);
            }
#pragma unroll
            for (int r = 0; r < 4; ++r)
                sc[(r4 + r) * SC_LD + ct * 16 + lrow] = a[r];
        }
        __syncthreads();

        // ---- softmax (16 lanes per row; causal; scale 1/8 folded into exp)
        {
            const int row = t >> 4, sub = t & 15;
            const int n = r0 + row;
            const bool wout = (n < N_TOK);
            const int nv = wout ? n : (N_TOK - 1);
            float mx = -1e30f;
            for (int m = sub; m <= nv; m += 16)
                mx = fmaxf(mx, sc[row * SC_LD + m]);
#pragma unroll
            for (int o = 1; o < 16; o <<= 1) mx = fmaxf(mx, __shfl_xor(mx, o));
            float sum = 0.f;
            for (int m = sub; m <= nv; m += 16) {
                float e = __expf((sc[row * SC_LD + m] - mx) * 0.125f);
                sc[row * SC_LD + m] = e;
                sum += e;
            }
#pragma unroll
            for (int o = 1; o < 16; o <<= 1) sum += __shfl_xor(sum, o);
            float inv = 1.0f / sum;
            size_t obase = 0;
            if (wout) {
                int b = bt / 12, tt2 = bt % 12;
                obase = ((((size_t)(h * 8 + b)) * 12 + tt2) * N_TOK + n) * N_TOK;
            }
            for (int m = sub; m < 352; m += 16) {
                float v = (wout && m <= nv) ? sc[row * SC_LD + m] * inv : 0.f;
                pa[row * PA_LD + m] = __float2bfloat16(v);
                if (wout && m < N_TOK) attn_out[obase + m] = v;
            }
        }
        __syncthreads();

        // ---- PV: wave handles output cols [wave*16, wave*16+16)
        f32x4 acc = {0.f, 0.f, 0.f, 0.f};
        const int nchunk = (rt + 2) >> 1;   // ceil((r0+16)/32)
        for (int s = 0; s < nchunk; ++s) {
            short8 aa = *(const short8*)&pa[lrow * PA_LD + s * 32 + lk8];
            short8 bb = *(const short8*)&Vt[(wave * 16 + lrow) * VT_LD + s * 32 + lk8];
            acc = __builtin_amdgcn_mfma_f32_16x16x32_bf16(aa, bb, acc, 0, 0, 0);
        }
#pragma unroll
        for (int r = 0; r < 4; ++r) {
            int n = r0 + r4 + r;
            if (n < N_TOK)
                qkv[(rowbase + n) * QKV_LD + h * 64 + wave * 16 + lrow] =
                    __float2bfloat16(acc[r]);
        }
    }
}

// ---------------------------------------------------------------------------
extern "C" void kernel_launch(void* const* d_in, const int* in_sizes, int n_in,
                              void* d_out, int out_size, void* d_ws, size_t ws_size,
                              hipStream_t stream)
{
    const void* X   = d_in[0];
    const void* STE = d_in[1];
    const void* Wq  = d_in[2];
    const void* bq  = d_in[3];
    const void* Wk  = d_in[4];
    const void* bk  = d_in[5];
    const void* Wv  = d_in[6];
    const void* bv  = d_in[7];
    const void* W1  = d_in[8];
    const void* b1  = d_in[9];
    const void* W2  = d_in[10];
    const void* b2  = d_in[11];

    float* out0     = (float*)d_out;                              // [31200][512] f32
    float* attn_out = (float*)d_out + (size_t)M_ROWS * D_MODEL;   // [64][12][325][325] f32

    char* ws = (char*)d_ws;
    bf16*  qkv   = (bf16*)(ws);                      // 95,846,400
    bf16*  BtQKV = (bf16*)(ws + 95846400);           //  3,145,728
    bf16*  W1T   = (bf16*)(ws + 98992128);           //    524,288
    bf16*  W2T   = (bf16*)(ws + 99516416);           //    524,288
    float* biasQ = (float*)(ws + 100040704);         //      6,144
    float* b1f   = (float*)(ws + 100046848);         //      2,048
    float* b2f   = (float*)(ws + 100048896);         //      2,048
    int*   flag  = (int*)(ws + 100050944);           //          4
    bf16*  hbuf  = qkv + 512;                        // FFN hidden aliases k-slice

    init_flag<<<1, 64, 0, stream>>>(flag);
    detect_dtype<<<64, 256, 0, stream>>>((const unsigned short*)X, flag);

    transpose_w_tiled<<<dim3(16, 32), 256, 0, stream>>>(Wq, BtQKV, 1024, 512, flag);
    transpose_w_tiled<<<dim3(16, 32), 256, 0, stream>>>(Wk, BtQKV + 512 * 1024, 1024, 512, flag);
    transpose_w_tiled<<<dim3(16, 32), 256, 0, stream>>>(Wv, BtQKV + 1024 * 1024, 1024, 512, flag);
    transpose_w_tiled<<<dim3(16, 16), 256, 0, stream>>>(W1, W1T, 512, 512, flag);
    transpose_w_tiled<<<dim3(16, 16), 256, 0, stream>>>(W2, W2T, 512, 512, flag);
    prep_bias<<<2, 256, 0, stream>>>(bq, bk, bv, b1, b2, biasQ, b1f, b2f, flag);

    // fused QKV projection: [31200,1024] x [1024,1536] (+bias, relu) -> bf16 ws
    gemm_bt<1, 0><<<dim3(244, 12), 256, 0, stream>>>(
        X, STE, 512, 512, BtQKV, biasQ, qkv, M_ROWS, 1024, QKV_LD, 1, flag);

    // attention (ctx -> q-slice of qkv; attn -> f32 d_out region)
    attn_kernel<<<768, 256, 0, stream>>>(qkv, attn_out);

    // FFN1: relu(ctx @ W1 + b1) -> hbuf (bf16, k-slice of qkv, ld 1536)
    gemm_bt<0, 0><<<dim3(244, 4), 256, 0, stream>>>(
        qkv, qkv, 512, QKV_LD, W1T, b1f, hbuf, M_ROWS, 512, QKV_LD, 1, flag);

    // FFN2: hbuf @ W2 + b2 -> out (f32)
    gemm_bt<0, 1><<<dim3(244, 4), 256, 0, stream>>>(
        hbuf, hbuf, 512, QKV_LD, W2T, b2f, out0, M_ROWS, 512, D_MODEL, 0, flag);
}

// Round 7
// 598.211 us; speedup vs baseline: 1.2172x; 1.2172x over previous
//
#include <hip/hip_runtime.h>
#include <hip/hip_bf16.h>

typedef __hip_bfloat16 bf16;
using f32x4  = __attribute__((ext_vector_type(4))) float;
using short8 = __attribute__((ext_vector_type(8))) short;

// B=8, T=12, N=325, K=8 heads, d=64, D=512, BT=96, M=31200
#define M_ROWS   31200
#define N_TOK    325
#define D_MODEL  512
#define QKV_LD   1536

// ---------------------------------------------------------------------------
// dtype detection: device inputs are either f32 or bf16 (flag=1 -> f32).
__global__ void init_flag(int* flag) { if (threadIdx.x == 0) *flag = 0; }

__global__ void detect_dtype(const unsigned short* __restrict__ x, int* flag)
{
    int i = blockIdx.x * 256 + threadIdx.x;   // 64 blocks * 256 = 16384 halves
    unsigned short h = x[i];
    int e = (h >> 7) & 0xFF;
    if (e >= 135) atomicOr(flag, 1);
}

__device__ __forceinline__ float load_in(const void* p, size_t i, bool f32)
{
    return f32 ? ((const float*)p)[i] : __bfloat162float(((const bf16*)p)[i]);
}

// ---------------------------------------------------------------------------
// tiled transpose: src [krows][ncols] -> dst [ncols][krows] bf16 (coalesced)
__global__ void transpose_w_tiled(const void* __restrict__ src, bf16* __restrict__ dst,
                                  int krows, int ncols, const int* __restrict__ flag)
{
    __shared__ float tile[32][33];
    const bool f32 = (*flag != 0);
    const int kt = blockIdx.y * 32, nt = blockIdx.x * 32;
    const int tx = threadIdx.x & 31, ty = threadIdx.x >> 5;   // 32 x 8
#pragma unroll
    for (int r = 0; r < 32; r += 8)
        tile[ty + r][tx] = load_in(src, (size_t)(kt + ty + r) * ncols + (nt + tx), f32);
    __syncthreads();
#pragma unroll
    for (int r = 0; r < 32; r += 8)
        dst[(size_t)(nt + ty + r) * krows + (kt + tx)] = __float2bfloat16(tile[tx][ty + r]);
}

__global__ void prep_bias(const void* __restrict__ bq, const void* __restrict__ bk,
                          const void* __restrict__ bv, const void* __restrict__ b1,
                          const void* __restrict__ b2,
                          float* __restrict__ biasQKV, float* __restrict__ b1f,
                          float* __restrict__ b2f, const int* __restrict__ flag)
{
    const bool f32 = (*flag != 0);
    int i = blockIdx.x * 256 + threadIdx.x;
    if (i < 512) {
        biasQKV[i]        = load_in(bq, i, f32);
        biasQKV[512 + i]  = load_in(bk, i, f32);
        biasQKV[1024 + i] = load_in(bv, i, f32);
        b1f[i] = load_in(b1, i, f32);
        b2f[i] = load_in(b2, i, f32);
    }
}

// ---------------------------------------------------------------------------
// 128x128-tile bf16-MFMA GEMM (verified round-4 baseline, unchanged)
template<int AMODE, int OUTF32>
__global__ __launch_bounds__(256) void gemm_bt(
    const void* __restrict__ A0v, const void* __restrict__ A1v, int ksplit, int lda,
    const bf16* __restrict__ Bt, const float* __restrict__ bias,
    void* __restrict__ Cv, int M, int Kdim, int ldc, int do_relu,
    const int* __restrict__ flag)
{
    __shared__ alignas(16) bf16 As[128 * 40];
    __shared__ alignas(16) bf16 Bs[128 * 40];
    const bool af32 = (AMODE == 1) && (*flag != 0);
    const int t    = threadIdx.x;
    const int m0   = blockIdx.x * 128;
    const int n0   = blockIdx.y * 128;
    const int wave = t >> 6, lane = t & 63;
    const int wm   = (wave >> 1) * 64, wn = (wave & 1) * 64;
    const int lrow = lane & 15, lk8 = (lane >> 4) * 8;
    f32x4 acc[4][4] = {};
    const int nk = Kdim >> 5;

    for (int ks = 0; ks < nk; ++ks) {
        const int kk = ks << 5;
#pragma unroll
        for (int i = 0; i < 2; ++i) {
            int idx = t + i * 256;
            int ar  = idx >> 2, ac = (idx & 3) << 3;
            int gk  = kk + ac;
            int grow = m0 + ar;
            short8 va = {0, 0, 0, 0, 0, 0, 0, 0};
            if (grow < M) {
                const bool lo = (gk < ksplit);
                const void* base = lo ? A0v : A1v;
                size_t off = (size_t)grow * lda + (lo ? gk : (gk - ksplit));
                if (af32) {
                    const float* s = (const float*)base + off;
#pragma unroll
                    for (int j = 0; j < 8; ++j)
                        ((bf16*)&va)[j] = __float2bfloat16(s[j]);
                } else {
                    va = *(const short8*)((const bf16*)base + off);
                }
            }
            *(short8*)&As[ar * 40 + ac] = va;
            *(uint4*)&Bs[ar * 40 + ac] =
                *(const uint4*)(Bt + (size_t)(n0 + ar) * Kdim + gk);
        }
        __syncthreads();
        short8 af[4], bfr[4];
#pragma unroll
        for (int i = 0; i < 4; ++i) {
            af[i]  = *(const short8*)&As[(wm + i * 16 + lrow) * 40 + lk8];
            bfr[i] = *(const short8*)&Bs[(wn + i * 16 + lrow) * 40 + lk8];
        }
#pragma unroll
        for (int i = 0; i < 4; ++i)
#pragma unroll
            for (int j = 0; j < 4; ++j)
                acc[i][j] = __builtin_amdgcn_mfma_f32_16x16x32_bf16(
                    af[i], bfr[j], acc[i][j], 0, 0, 0);
        __syncthreads();
    }

    const int r4 = (lane >> 4) * 4;
#pragma unroll
    for (int i = 0; i < 4; ++i) {
#pragma unroll
        for (int r = 0; r < 4; ++r) {
            int grow = m0 + wm + i * 16 + r4 + r;
            if (grow >= M) continue;
#pragma unroll
            for (int j = 0; j < 4; ++j) {
                int gcol = n0 + wn + j * 16 + lrow;
                float v  = acc[i][j][r] + bias[gcol];
                if (do_relu) v = fmaxf(v, 0.0f);
                if (OUTF32)
                    ((float*)Cv)[(size_t)grow * ldc + gcol] = v;
                else
                    ((bf16*)Cv)[(size_t)grow * ldc + gcol] = __float2bfloat16(v);
            }
        }
    }
}

// ---------------------------------------------------------------------------
// Attention v3: one block per (bt, h), 512 threads (8 waves), 2 row-tiles
// in flight (waves 0-3 -> even tile, 4-7 -> odd tile). K resident [336][72]
// zero-padded; V resident transposed [64][354]. Q held in registers (each
// lane loads its own 2x16B fragment from global). sc/pa doubled for the two
// tile groups. LDS = 159,296 B -> 1 block/CU but 2 waves/SIMD (v2.1 had 1).
#define KS_LD  72
#define VT_LD  354
#define SC_LD  336
#define PA_LD  352
__global__ __launch_bounds__(512) void attn_kernel(
    bf16* __restrict__ qkv, float* __restrict__ attn_out)
{
    __shared__ alignas(16) bf16  Ks[336 * KS_LD];        // 48384 B
    __shared__ alignas(16) bf16  Vt[64 * VT_LD + 32];    // 45376 B
    __shared__ alignas(16) float sc[2 * 16 * SC_LD];     // 43008 B
    __shared__ alignas(16) bf16  pa[2 * 16 * PA_LD];     // 22528 B
    const int t = threadIdx.x, lane = t & 63, wave = t >> 6;
    const int g = wave >> 2, wg = wave & 3;              // tile-group, role
    const int h = blockIdx.x & 7, bt = blockIdx.x >> 3;
    const size_t rowbase = (size_t)bt * N_TOK;
    const int lrow = lane & 15, lk8 = (lane >> 4) * 8;
    const int r4 = (lane >> 4) * 4;
    float* scg = sc + g * 16 * SC_LD;
    bf16*  pag = pa + g * 16 * PA_LD;

    // ---- stage K (rows 0..335, zero-padded)
    for (int task = t; task < 336 * 8; task += 512) {
        int m = task >> 3, e0 = (task & 7) << 3;
        short8 v = {0, 0, 0, 0, 0, 0, 0, 0};
        if (m < N_TOK)
            v = *(const short8*)(qkv + (rowbase + m) * QKV_LD + 512 + h * 64 + e0);
        *(short8*)&Ks[m * KS_LD + e0] = v;
    }
    // ---- stage V transposed (cols 0..351, zero-padded)
    for (int task = t; task < 352 * 8; task += 512) {
        int m = task >> 3, e0 = (task & 7) << 3;
        short8 v = {0, 0, 0, 0, 0, 0, 0, 0};
        if (m < N_TOK)
            v = *(const short8*)(qkv + (rowbase + m) * QKV_LD + 1024 + h * 64 + e0);
#pragma unroll
        for (int j = 0; j < 8; ++j)
            Vt[(e0 + j) * VT_LD + m] = ((bf16*)&v)[j];
    }
    __syncthreads();

    for (int it = 0; it < 11; ++it) {
        const int tile = it * 2 + g;                 // waves 0-3: even, 4-7: odd
        const bool tvalid = (tile <= 20);
        const int r0 = tile * 16;

        // ---- Q fragment in registers (lane's own row, clamped; dead rows unused)
        short8 qa0 = {0,0,0,0,0,0,0,0}, qa1 = {0,0,0,0,0,0,0,0};
        if (tvalid) {
            int qrow = r0 + lrow; if (qrow > N_TOK - 1) qrow = N_TOK - 1;
            const bf16* qp = qkv + (rowbase + qrow) * QKV_LD + h * 64 + lk8;
            qa0 = *(const short8*)(qp);
            qa1 = *(const short8*)(qp + 32);
        }

        // ---- QK^T: col-tiles ct = wg, wg+4, ... <= tile
        if (tvalid) {
            for (int ct = wg; ct <= tile; ct += 4) {
                f32x4 a = {0.f, 0.f, 0.f, 0.f};
                short8 kb0 = *(const short8*)&Ks[(ct * 16 + lrow) * KS_LD + lk8];
                short8 kb1 = *(const short8*)&Ks[(ct * 16 + lrow) * KS_LD + 32 + lk8];
                a = __builtin_amdgcn_mfma_f32_16x16x32_bf16(qa0, kb0, a, 0, 0, 0);
                a = __builtin_amdgcn_mfma_f32_16x16x32_bf16(qa1, kb1, a, 0, 0, 0);
#pragma unroll
                for (int r = 0; r < 4; ++r)
                    scg[(r4 + r) * SC_LD + ct * 16 + lrow] = a[r];
            }
        }
        __syncthreads();

        // ---- softmax: 32 rows x 16 lanes (both tile groups at once)
        {
            const int row = t >> 4, sub = t & 15;
            const int rg = row >> 4, rl = row & 15;
            const int rtile = it * 2 + rg;
            float* scr = sc + rg * 16 * SC_LD + rl * SC_LD;
            bf16*  par = pa + rg * 16 * PA_LD + rl * PA_LD;
            const int n = rtile * 16 + rl;
            const bool wout = (rtile <= 20) && (n < N_TOK);
            const int nv = wout ? n : 0;
            if (rtile <= 20) {
                float mx = -1e30f;
                for (int m = sub; m <= nv; m += 16)
                    mx = fmaxf(mx, scr[m]);
#pragma unroll
                for (int o = 1; o < 16; o <<= 1) mx = fmaxf(mx, __shfl_xor(mx, o));
                float sum = 0.f;
                for (int m = sub; m <= nv; m += 16) {
                    float e = __expf((scr[m] - mx) * 0.125f);
                    scr[m] = e;
                    sum += e;
                }
#pragma unroll
                for (int o = 1; o < 16; o <<= 1) sum += __shfl_xor(sum, o);
                float inv = 1.0f / sum;
                size_t obase = 0;
                if (wout) {
                    int b = bt / 12, tt2 = bt % 12;
                    obase = ((((size_t)(h * 8 + b)) * 12 + tt2) * N_TOK + n) * N_TOK;
                }
                for (int m = sub; m < 352; m += 16) {
                    float v = (wout && m <= nv) ? scr[m] * inv : 0.f;
                    par[m] = __float2bfloat16(v);
                    if (wout && m < N_TOK) attn_out[obase + m] = v;
                }
            }
        }
        __syncthreads();

        // ---- PV: role wg handles output cols [wg*16, wg*16+16)
        if (tvalid) {
            f32x4 acc = {0.f, 0.f, 0.f, 0.f};
            const int nchunk = (tile + 2) >> 1;      // ceil((r0+16)/32)
            for (int s = 0; s < nchunk; ++s) {
                short8 aa = *(const short8*)&pag[lrow * PA_LD + s * 32 + lk8];
                short8 bb = *(const short8*)&Vt[(wg * 16 + lrow) * VT_LD + s * 32 + lk8];
                acc = __builtin_amdgcn_mfma_f32_16x16x32_bf16(aa, bb, acc, 0, 0, 0);
            }
#pragma unroll
            for (int r = 0; r < 4; ++r) {
                int n = r0 + r4 + r;
                if (n < N_TOK)
                    qkv[(rowbase + n) * QKV_LD + h * 64 + wg * 16 + lrow] =
                        __float2bfloat16(acc[r]);
            }
        }
    }
}

// ---------------------------------------------------------------------------
extern "C" void kernel_launch(void* const* d_in, const int* in_sizes, int n_in,
                              void* d_out, int out_size, void* d_ws, size_t ws_size,
                              hipStream_t stream)
{
    const void* X   = d_in[0];
    const void* STE = d_in[1];
    const void* Wq  = d_in[2];
    const void* bq  = d_in[3];
    const void* Wk  = d_in[4];
    const void* bk  = d_in[5];
    const void* Wv  = d_in[6];
    const void* bv  = d_in[7];
    const void* W1  = d_in[8];
    const void* b1  = d_in[9];
    const void* W2  = d_in[10];
    const void* b2  = d_in[11];

    float* out0     = (float*)d_out;                              // [31200][512] f32
    float* attn_out = (float*)d_out + (size_t)M_ROWS * D_MODEL;   // [64][12][325][325] f32

    char* ws = (char*)d_ws;
    bf16*  qkv   = (bf16*)(ws);                      // 95,846,400
    bf16*  BtQKV = (bf16*)(ws + 95846400);           //  3,145,728
    bf16*  W1T   = (bf16*)(ws + 98992128);           //    524,288
    bf16*  W2T   = (bf16*)(ws + 99516416);           //    524,288
    float* biasQ = (float*)(ws + 100040704);         //      6,144
    float* b1f   = (float*)(ws + 100046848);         //      2,048
    float* b2f   = (float*)(ws + 100048896);         //      2,048
    int*   flag  = (int*)(ws + 100050944);           //          4
    bf16*  hbuf  = qkv + 512;                        // FFN hidden aliases k-slice

    init_flag<<<1, 64, 0, stream>>>(flag);
    detect_dtype<<<64, 256, 0, stream>>>((const unsigned short*)X, flag);

    transpose_w_tiled<<<dim3(16, 32), 256, 0, stream>>>(Wq, BtQKV, 1024, 512, flag);
    transpose_w_tiled<<<dim3(16, 32), 256, 0, stream>>>(Wk, BtQKV + 512 * 1024, 1024, 512, flag);
    transpose_w_tiled<<<dim3(16, 32), 256, 0, stream>>>(Wv, BtQKV + 1024 * 1024, 1024, 512, flag);
    transpose_w_tiled<<<dim3(16, 16), 256, 0, stream>>>(W1, W1T, 512, 512, flag);
    transpose_w_tiled<<<dim3(16, 16), 256, 0, stream>>>(W2, W2T, 512, 512, flag);
    prep_bias<<<2, 256, 0, stream>>>(bq, bk, bv, b1, b2, biasQ, b1f, b2f, flag);

    // fused QKV projection: [31200,1024] x [1024,1536] (+bias, relu) -> bf16 ws
    gemm_bt<1, 0><<<dim3(244, 12), 256, 0, stream>>>(
        X, STE, 512, 512, BtQKV, biasQ, qkv, M_ROWS, 1024, QKV_LD, 1, flag);

    // attention (ctx -> q-slice of qkv; attn -> f32 d_out region)
    attn_kernel<<<768, 512, 0, stream>>>(qkv, attn_out);

    // FFN1: relu(ctx @ W1 + b1) -> hbuf (bf16, k-slice of qkv, ld 1536)
    gemm_bt<0, 0><<<dim3(244, 4), 256, 0, stream>>>(
        qkv, qkv, 512, QKV_LD, W1T, b1f, hbuf, M_ROWS, 512, QKV_LD, 1, flag);

    // FFN2: hbuf @ W2 + b2 -> out (f32)
    gemm_bt<0, 1><<<dim3(244, 4), 256, 0, stream>>>(
        hbuf, hbuf, 512, QKV_LD, W2T, b2f, out0, M_ROWS, 512, D_MODEL, 0, flag);
}

// Round 8
// 521.319 us; speedup vs baseline: 1.3968x; 1.1475x over previous
//
#include <hip/hip_runtime.h>
#include <hip/hip_bf16.h>

typedef __hip_bfloat16 bf16;
using f32x4  = __attribute__((ext_vector_type(4))) float;
using short8 = __attribute__((ext_vector_type(8))) short;

// B=8, T=12, N=325, K=8 heads, d=64, D=512, BT=96, M=31200 (padded 31232)
#define M_ROWS   31200
#define M_PAD    31232
#define N_TOK    325
#define D_MODEL  512
#define QKV_LD   1536

#define GLOBAL_AS(p) ((const __attribute__((address_space(1))) unsigned int*)(p))
#define LDS_AS(p)    ((__attribute__((address_space(3))) unsigned int*)(p))

// ---------------------------------------------------------------------------
// dtype detection: device inputs are either f32 or bf16 (flag=1 -> f32).
__global__ void init_flag(int* flag) { if (threadIdx.x == 0) *flag = 0; }

__global__ void detect_dtype(const unsigned short* __restrict__ x, int* flag)
{
    int i = blockIdx.x * 256 + threadIdx.x;   // 64 blocks * 256 = 16384 halves
    unsigned short h = x[i];
    int e = (h >> 7) & 0xFF;
    if (e >= 135) atomicOr(flag, 1);
}

__device__ __forceinline__ float load_in(const void* p, size_t i, bool f32)
{
    return f32 ? ((const float*)p)[i] : __bfloat162float(((const bf16*)p)[i]);
}

// ---------------------------------------------------------------------------
// concat(X,STE) -> bf16 Xc[31232][1024]; rows >= 31200 zeroed.
__global__ void concat_cast(const void* __restrict__ X, const void* __restrict__ STE,
                            bf16* __restrict__ Xc, const int* __restrict__ flag)
{
    const bool f32 = (*flag != 0);
    int idx = blockIdx.x * 256 + threadIdx.x;       // M_PAD*128 tasks of 8 elems
    int r = idx >> 7, c8 = (idx & 127) << 3;
    short8 v = {0, 0, 0, 0, 0, 0, 0, 0};
    if (r < M_ROWS) {
        const void* src = (c8 < 512) ? X : STE;
        int cc = c8 & 511;
        if (f32) {
            const float* s = (const float*)src + (size_t)r * 512 + cc;
            float4 a = *(const float4*)s;
            float4 b = *(const float4*)(s + 4);
            ((bf16*)&v)[0] = __float2bfloat16(a.x); ((bf16*)&v)[1] = __float2bfloat16(a.y);
            ((bf16*)&v)[2] = __float2bfloat16(a.z); ((bf16*)&v)[3] = __float2bfloat16(a.w);
            ((bf16*)&v)[4] = __float2bfloat16(b.x); ((bf16*)&v)[5] = __float2bfloat16(b.y);
            ((bf16*)&v)[6] = __float2bfloat16(b.z); ((bf16*)&v)[7] = __float2bfloat16(b.w);
        } else {
            v = *(const short8*)((const bf16*)src + (size_t)r * 512 + cc);
        }
    }
    *(short8*)&Xc[(size_t)r * 1024 + c8] = v;
}

// ---------------------------------------------------------------------------
// tiled transpose: src [krows][ncols] -> dst [ncols][krows] bf16 (coalesced)
__global__ void transpose_w_tiled(const void* __restrict__ src, bf16* __restrict__ dst,
                                  int krows, int ncols, const int* __restrict__ flag)
{
    __shared__ float tile[32][33];
    const bool f32 = (*flag != 0);
    const int kt = blockIdx.y * 32, nt = blockIdx.x * 32;
    const int tx = threadIdx.x & 31, ty = threadIdx.x >> 5;   // 32 x 8
#pragma unroll
    for (int r = 0; r < 32; r += 8)
        tile[ty + r][tx] = load_in(src, (size_t)(kt + ty + r) * ncols + (nt + tx), f32);
    __syncthreads();
#pragma unroll
    for (int r = 0; r < 32; r += 8)
        dst[(size_t)(nt + ty + r) * krows + (kt + tx)] = __float2bfloat16(tile[tx][ty + r]);
}

__global__ void prep_bias(const void* __restrict__ bq, const void* __restrict__ bk,
                          const void* __restrict__ bv, const void* __restrict__ b1,
                          const void* __restrict__ b2,
                          float* __restrict__ biasQKV, float* __restrict__ b1f,
                          float* __restrict__ b2f, const int* __restrict__ flag)
{
    const bool f32 = (*flag != 0);
    int i = blockIdx.x * 256 + threadIdx.x;
    if (i < 512) {
        biasQKV[i]        = load_in(bq, i, f32);
        biasQKV[512 + i]  = load_in(bk, i, f32);
        biasQKV[1024 + i] = load_in(bv, i, f32);
        b1f[i] = load_in(b1, i, f32);
        b2f[i] = load_in(b2, i, f32);
    }
}

// ---------------------------------------------------------------------------
// m97-style 128x128 GEMM: C = act(A @ Bt^T + bias). BK=32, linear LDS,
// global_load_lds dwordx4 staging, bijective XCD blockIdx swizzle.
// A [Mpad][lda] bf16 (Mpad % 128 == 0, no M guards on loads);
// Bt [N][ldb] bf16. OUTF32=1 guards stores at Mvalid (f32 d_out).
template<int OUTF32>
__global__ __launch_bounds__(256) void gemm_lds(
    const bf16* __restrict__ A, int lda,
    const bf16* __restrict__ Bt, int ldb,
    const float* __restrict__ bias, void* __restrict__ Cv,
    int Mvalid, int Kdim, int ldc, int do_relu, int nbx)
{
    __shared__ alignas(16) bf16 As[128 * 32];
    __shared__ alignas(16) bf16 Bs[128 * 32];
    // bijective XCD swizzle (gridDim.x % 8 == 0)
    const int cpx = gridDim.x >> 3;
    const int swz = (blockIdx.x & 7) * cpx + (blockIdx.x >> 3);
    const int m0 = (swz % nbx) * 128;
    const int n0 = (swz / nbx) * 128;
    const int t = threadIdx.x, wave = t >> 6, lane = t & 63;
    const int wm = (wave >> 1) * 64, wn = (wave & 1) * 64;
    const int lrow = lane & 15, lk8 = (lane >> 4) * 8;
    const int srow = lane >> 2, scol = (lane & 3) << 3;   // staging row/col
    f32x4 acc[4][4] = {};
    const int nk = Kdim >> 5;

    for (int ks = 0; ks < nk; ++ks) {
        const int kk = ks << 5;
        __syncthreads();   // previous tile's LDS reads complete
#pragma unroll
        for (int c = 0; c < 2; ++c) {
            const int chunk = wave * 2 + c;            // 0..7, 16 rows each
            const bf16* ga = A  + (size_t)(m0 + chunk * 16 + srow) * lda + kk + scol;
            const bf16* gb = Bt + (size_t)(n0 + chunk * 16 + srow) * ldb + kk + scol;
            __builtin_amdgcn_global_load_lds(GLOBAL_AS(ga), LDS_AS(As + chunk * 512), 16, 0, 0);
            __builtin_amdgcn_global_load_lds(GLOBAL_AS(gb), LDS_AS(Bs + chunk * 512), 16, 0, 0);
        }
        __syncthreads();   // staging complete (compiler drains vmcnt)
        short8 af[4], bfr[4];
#pragma unroll
        for (int i = 0; i < 4; ++i) {
            af[i]  = *(const short8*)&As[(wm + i * 16 + lrow) * 32 + lk8];
            bfr[i] = *(const short8*)&Bs[(wn + i * 16 + lrow) * 32 + lk8];
        }
#pragma unroll
        for (int i = 0; i < 4; ++i)
#pragma unroll
            for (int j = 0; j < 4; ++j)
                acc[i][j] = __builtin_amdgcn_mfma_f32_16x16x32_bf16(
                    af[i], bfr[j], acc[i][j], 0, 0, 0);
    }

    const int r4 = (lane >> 4) * 4;
#pragma unroll
    for (int i = 0; i < 4; ++i) {
#pragma unroll
        for (int r = 0; r < 4; ++r) {
            int grow = m0 + wm + i * 16 + r4 + r;
            if (OUTF32 && grow >= Mvalid) continue;
#pragma unroll
            for (int j = 0; j < 4; ++j) {
                int gcol = n0 + wn + j * 16 + lrow;
                float v  = acc[i][j][r] + bias[gcol];
                if (do_relu) v = fmaxf(v, 0.0f);
                if (OUTF32)
                    ((float*)Cv)[(size_t)grow * ldc + gcol] = v;
                else
                    ((bf16*)Cv)[(size_t)grow * ldc + gcol] = __float2bfloat16(v);
            }
        }
    }
}

// ---------------------------------------------------------------------------
// Attention v3 (verified round 7, unchanged): one block per (bt, h),
// 512 threads (8 waves), 2 row-tiles in flight. K resident [336][72];
// V resident transposed [64][354]; Q in registers. LDS 159,296 B.
#define KS_LD  72
#define VT_LD  354
#define SC_LD  336
#define PA_LD  352
__global__ __launch_bounds__(512) void attn_kernel(
    bf16* __restrict__ qkv, float* __restrict__ attn_out)
{
    __shared__ alignas(16) bf16  Ks[336 * KS_LD];        // 48384 B
    __shared__ alignas(16) bf16  Vt[64 * VT_LD + 32];    // 45376 B
    __shared__ alignas(16) float sc[2 * 16 * SC_LD];     // 43008 B
    __shared__ alignas(16) bf16  pa[2 * 16 * PA_LD];     // 22528 B
    const int t = threadIdx.x, lane = t & 63, wave = t >> 6;
    const int g = wave >> 2, wg = wave & 3;              // tile-group, role
    const int h = blockIdx.x & 7, bt = blockIdx.x >> 3;
    const size_t rowbase = (size_t)bt * N_TOK;
    const int lrow = lane & 15, lk8 = (lane >> 4) * 8;
    const int r4 = (lane >> 4) * 4;
    float* scg = sc + g * 16 * SC_LD;
    bf16*  pag = pa + g * 16 * PA_LD;

    for (int task = t; task < 336 * 8; task += 512) {
        int m = task >> 3, e0 = (task & 7) << 3;
        short8 v = {0, 0, 0, 0, 0, 0, 0, 0};
        if (m < N_TOK)
            v = *(const short8*)(qkv + (rowbase + m) * QKV_LD + 512 + h * 64 + e0);
        *(short8*)&Ks[m * KS_LD + e0] = v;
    }
    for (int task = t; task < 352 * 8; task += 512) {
        int m = task >> 3, e0 = (task & 7) << 3;
        short8 v = {0, 0, 0, 0, 0, 0, 0, 0};
        if (m < N_TOK)
            v = *(const short8*)(qkv + (rowbase + m) * QKV_LD + 1024 + h * 64 + e0);
#pragma unroll
        for (int j = 0; j < 8; ++j)
            Vt[(e0 + j) * VT_LD + m] = ((bf16*)&v)[j];
    }
    __syncthreads();

    for (int it = 0; it < 11; ++it) {
        const int tile = it * 2 + g;
        const bool tvalid = (tile <= 20);
        const int r0 = tile * 16;

        short8 qa0 = {0,0,0,0,0,0,0,0}, qa1 = {0,0,0,0,0,0,0,0};
        if (tvalid) {
            int qrow = r0 + lrow; if (qrow > N_TOK - 1) qrow = N_TOK - 1;
            const bf16* qp = qkv + (rowbase + qrow) * QKV_LD + h * 64 + lk8;
            qa0 = *(const short8*)(qp);
            qa1 = *(const short8*)(qp + 32);
        }

        if (tvalid) {
            for (int ct = wg; ct <= tile; ct += 4) {
                f32x4 a = {0.f, 0.f, 0.f, 0.f};
                short8 kb0 = *(const short8*)&Ks[(ct * 16 + lrow) * KS_LD + lk8];
                short8 kb1 = *(const short8*)&Ks[(ct * 16 + lrow) * KS_LD + 32 + lk8];
                a = __builtin_amdgcn_mfma_f32_16x16x32_bf16(qa0, kb0, a, 0, 0, 0);
                a = __builtin_amdgcn_mfma_f32_16x16x32_bf16(qa1, kb1, a, 0, 0, 0);
#pragma unroll
                for (int r = 0; r < 4; ++r)
                    scg[(r4 + r) * SC_LD + ct * 16 + lrow] = a[r];
            }
        }
        __syncthreads();

        {
            const int row = t >> 4, sub = t & 15;
            const int rg = row >> 4, rl = row & 15;
            const int rtile = it * 2 + rg;
            float* scr = sc + rg * 16 * SC_LD + rl * SC_LD;
            bf16*  par = pa + rg * 16 * PA_LD + rl * PA_LD;
            const int n = rtile * 16 + rl;
            const bool wout = (rtile <= 20) && (n < N_TOK);
            const int nv = wout ? n : 0;
            if (rtile <= 20) {
                float mx = -1e30f;
                for (int m = sub; m <= nv; m += 16)
                    mx = fmaxf(mx, scr[m]);
#pragma unroll
                for (int o = 1; o < 16; o <<= 1) mx = fmaxf(mx, __shfl_xor(mx, o));
                float sum = 0.f;
                for (int m = sub; m <= nv; m += 16) {
                    float e = __expf((scr[m] - mx) * 0.125f);
                    scr[m] = e;
                    sum += e;
                }
#pragma unroll
                for (int o = 1; o < 16; o <<= 1) sum += __shfl_xor(sum, o);
                float inv = 1.0f / sum;
                size_t obase = 0;
                if (wout) {
                    int b = bt / 12, tt2 = bt % 12;
                    obase = ((((size_t)(h * 8 + b)) * 12 + tt2) * N_TOK + n) * N_TOK;
                }
                for (int m = sub; m < 352; m += 16) {
                    float v = (wout && m <= nv) ? scr[m] * inv : 0.f;
                    par[m] = __float2bfloat16(v);
                    if (wout && m < N_TOK) attn_out[obase + m] = v;
                }
            }
        }
        __syncthreads();

        if (tvalid) {
            f32x4 acc = {0.f, 0.f, 0.f, 0.f};
            const int nchunk = (tile + 2) >> 1;
            for (int s = 0; s < nchunk; ++s) {
                short8 aa = *(const short8*)&pag[lrow * PA_LD + s * 32 + lk8];
                short8 bb = *(const short8*)&Vt[(wg * 16 + lrow) * VT_LD + s * 32 + lk8];
                acc = __builtin_amdgcn_mfma_f32_16x16x32_bf16(aa, bb, acc, 0, 0, 0);
            }
#pragma unroll
            for (int r = 0; r < 4; ++r) {
                int n = r0 + r4 + r;
                if (n < N_TOK)
                    qkv[(rowbase + n) * QKV_LD + h * 64 + wg * 16 + lrow] =
                        __float2bfloat16(acc[r]);
            }
        }
    }
}

// ---------------------------------------------------------------------------
extern "C" void kernel_launch(void* const* d_in, const int* in_sizes, int n_in,
                              void* d_out, int out_size, void* d_ws, size_t ws_size,
                              hipStream_t stream)
{
    const void* X   = d_in[0];
    const void* STE = d_in[1];
    const void* Wq  = d_in[2];
    const void* bq  = d_in[3];
    const void* Wk  = d_in[4];
    const void* bk  = d_in[5];
    const void* Wv  = d_in[6];
    const void* bv  = d_in[7];
    const void* W1  = d_in[8];
    const void* b1  = d_in[9];
    const void* W2  = d_in[10];
    const void* b2  = d_in[11];

    float* out0     = (float*)d_out;                              // [31200][512] f32
    float* attn_out = (float*)d_out + (size_t)M_ROWS * D_MODEL;   // [64][12][325][325] f32
    // Xc scratch lives in the attn_out region (dead until attn_kernel runs,
    // which fully overwrites it afterwards; all sequential on `stream`).
    bf16*  Xc       = (bf16*)attn_out;                            // 63,963,136 B

    char* ws = (char*)d_ws;
    bf16*  qkv   = (bf16*)(ws);                      // 31232*1536*2 = 95,944,704
    bf16*  BtQKV = (bf16*)(ws + 95944704);           //  3,145,728
    bf16*  W1T   = (bf16*)(ws + 99090432);           //    524,288
    bf16*  W2T   = (bf16*)(ws + 99614720);           //    524,288
    float* biasQ = (float*)(ws + 100139008);         //      6,144
    float* b1f   = (float*)(ws + 100145152);         //      2,048
    float* b2f   = (float*)(ws + 100147200);         //      2,048
    int*   flag  = (int*)(ws + 100149248);           //          4
    bf16*  hbuf  = qkv + 512;                        // FFN hidden aliases k-slice

    init_flag<<<1, 64, 0, stream>>>(flag);
    detect_dtype<<<64, 256, 0, stream>>>((const unsigned short*)X, flag);

    transpose_w_tiled<<<dim3(16, 32), 256, 0, stream>>>(Wq, BtQKV, 1024, 512, flag);
    transpose_w_tiled<<<dim3(16, 32), 256, 0, stream>>>(Wk, BtQKV + 512 * 1024, 1024, 512, flag);
    transpose_w_tiled<<<dim3(16, 32), 256, 0, stream>>>(Wv, BtQKV + 1024 * 1024, 1024, 512, flag);
    transpose_w_tiled<<<dim3(16, 16), 256, 0, stream>>>(W1, W1T, 512, 512, flag);
    transpose_w_tiled<<<dim3(16, 16), 256, 0, stream>>>(W2, W2T, 512, 512, flag);
    prep_bias<<<2, 256, 0, stream>>>(bq, bk, bv, b1, b2, biasQ, b1f, b2f, flag);

    // concat(X,STE) -> bf16 Xc [31232][1024]
    concat_cast<<<(M_PAD * 128) / 256, 256, 0, stream>>>(X, STE, Xc, flag);

    // QKV projection: Xc[31232,1024] @ BtQKV^T -> qkv (+bias, relu)
    gemm_lds<0><<<244 * 12, 256, 0, stream>>>(
        Xc, 1024, BtQKV, 1024, biasQ, qkv, M_PAD, 1024, QKV_LD, 1, 244);

    // attention (ctx -> q-slice of qkv; attn -> f32 d_out region, overwrites Xc)
    attn_kernel<<<768, 512, 0, stream>>>(qkv, attn_out);

    // FFN1: relu(ctx @ W1 + b1) -> hbuf (k-slice of qkv)
    gemm_lds<0><<<244 * 4, 256, 0, stream>>>(
        qkv, QKV_LD, W1T, 512, b1f, hbuf, M_PAD, 512, QKV_LD, 1, 244);

    // FFN2: hbuf @ W2 + b2 -> out0 (f32, guarded at M_ROWS)
    gemm_lds<1><<<244 * 4, 256, 0, stream>>>(
        hbuf, QKV_LD, W2T, 512, b2f, out0, M_ROWS, 512, D_MODEL, 0, 244);
}

// Round 9
// 452.567 us; speedup vs baseline: 1.6090x; 1.1519x over previous
//
#include <hip/hip_runtime.h>
#include <hip/hip_bf16.h>

typedef __hip_bfloat16 bf16;
using f32x4  = __attribute__((ext_vector_type(4))) float;
using short8 = __attribute__((ext_vector_type(8))) short;

// B=8, T=12, N=325, K=8 heads, d=64, D=512, BT=96, M=31200 (padded 31232)
#define M_ROWS   31200
#define M_PAD    31232
#define N_TOK    325
#define D_MODEL  512
#define QKV_LD   1536

#define GLOBAL_AS(p) ((const __attribute__((address_space(1))) unsigned int*)(p))
#define LDS_AS(p)    ((__attribute__((address_space(3))) unsigned int*)(p))

// ---------------------------------------------------------------------------
// dtype detection: device inputs are either f32 or bf16 (flag=1 -> f32).
__global__ void init_flag(int* flag) { if (threadIdx.x == 0) *flag = 0; }

__global__ void detect_dtype(const unsigned short* __restrict__ x, int* flag)
{
    int i = blockIdx.x * 256 + threadIdx.x;   // 64 blocks * 256 = 16384 halves
    unsigned short h = x[i];
    int e = (h >> 7) & 0xFF;
    if (e >= 135) atomicOr(flag, 1);
}

__device__ __forceinline__ float load_in(const void* p, size_t i, bool f32)
{
    return f32 ? ((const float*)p)[i] : __bfloat162float(((const bf16*)p)[i]);
}

// ---------------------------------------------------------------------------
// concat(X,STE) -> bf16 Xc[31232][1024]; rows >= 31200 zeroed.
__global__ void concat_cast(const void* __restrict__ X, const void* __restrict__ STE,
                            bf16* __restrict__ Xc, const int* __restrict__ flag)
{
    const bool f32 = (*flag != 0);
    int idx = blockIdx.x * 256 + threadIdx.x;       // M_PAD*128 tasks of 8 elems
    int r = idx >> 7, c8 = (idx & 127) << 3;
    short8 v = {0, 0, 0, 0, 0, 0, 0, 0};
    if (r < M_ROWS) {
        const void* src = (c8 < 512) ? X : STE;
        int cc = c8 & 511;
        if (f32) {
            const float* s = (const float*)src + (size_t)r * 512 + cc;
            float4 a = *(const float4*)s;
            float4 b = *(const float4*)(s + 4);
            ((bf16*)&v)[0] = __float2bfloat16(a.x); ((bf16*)&v)[1] = __float2bfloat16(a.y);
            ((bf16*)&v)[2] = __float2bfloat16(a.z); ((bf16*)&v)[3] = __float2bfloat16(a.w);
            ((bf16*)&v)[4] = __float2bfloat16(b.x); ((bf16*)&v)[5] = __float2bfloat16(b.y);
            ((bf16*)&v)[6] = __float2bfloat16(b.z); ((bf16*)&v)[7] = __float2bfloat16(b.w);
        } else {
            v = *(const short8*)((const bf16*)src + (size_t)r * 512 + cc);
        }
    }
    *(short8*)&Xc[(size_t)r * 1024 + c8] = v;
}

// ---------------------------------------------------------------------------
// tiled transpose: src [krows][ncols] -> dst [ncols][krows] bf16 (coalesced)
__global__ void transpose_w_tiled(const void* __restrict__ src, bf16* __restrict__ dst,
                                  int krows, int ncols, const int* __restrict__ flag)
{
    __shared__ float tile[32][33];
    const bool f32 = (*flag != 0);
    const int kt = blockIdx.y * 32, nt = blockIdx.x * 32;
    const int tx = threadIdx.x & 31, ty = threadIdx.x >> 5;   // 32 x 8
#pragma unroll
    for (int r = 0; r < 32; r += 8)
        tile[ty + r][tx] = load_in(src, (size_t)(kt + ty + r) * ncols + (nt + tx), f32);
    __syncthreads();
#pragma unroll
    for (int r = 0; r < 32; r += 8)
        dst[(size_t)(nt + ty + r) * krows + (kt + tx)] = __float2bfloat16(tile[tx][ty + r]);
}

__global__ void prep_bias(const void* __restrict__ bq, const void* __restrict__ bk,
                          const void* __restrict__ bv, const void* __restrict__ b1,
                          const void* __restrict__ b2,
                          float* __restrict__ biasQKV, float* __restrict__ b1f,
                          float* __restrict__ b2f, const int* __restrict__ flag)
{
    const bool f32 = (*flag != 0);
    int i = blockIdx.x * 256 + threadIdx.x;
    if (i < 512) {
        biasQKV[i]        = load_in(bq, i, f32);
        biasQKV[512 + i]  = load_in(bk, i, f32);
        biasQKV[1024 + i] = load_in(bv, i, f32);
        b1f[i] = load_in(b1, i, f32);
        b2f[i] = load_in(b2, i, f32);
    }
}

// ---------------------------------------------------------------------------
// m97-style 128x128 GEMM (verified round 8, unchanged): BK=32, linear LDS,
// global_load_lds dwordx4 staging, bijective XCD blockIdx swizzle.
template<int OUTF32>
__global__ __launch_bounds__(256) void gemm_lds(
    const bf16* __restrict__ A, int lda,
    const bf16* __restrict__ Bt, int ldb,
    const float* __restrict__ bias, void* __restrict__ Cv,
    int Mvalid, int Kdim, int ldc, int do_relu, int nbx)
{
    __shared__ alignas(16) bf16 As[128 * 32];
    __shared__ alignas(16) bf16 Bs[128 * 32];
    const int cpx = gridDim.x >> 3;
    const int swz = (blockIdx.x & 7) * cpx + (blockIdx.x >> 3);
    const int m0 = (swz % nbx) * 128;
    const int n0 = (swz / nbx) * 128;
    const int t = threadIdx.x, wave = t >> 6, lane = t & 63;
    const int wm = (wave >> 1) * 64, wn = (wave & 1) * 64;
    const int lrow = lane & 15, lk8 = (lane >> 4) * 8;
    const int srow = lane >> 2, scol = (lane & 3) << 3;
    f32x4 acc[4][4] = {};
    const int nk = Kdim >> 5;

    for (int ks = 0; ks < nk; ++ks) {
        const int kk = ks << 5;
        __syncthreads();
#pragma unroll
        for (int c = 0; c < 2; ++c) {
            const int chunk = wave * 2 + c;
            const bf16* ga = A  + (size_t)(m0 + chunk * 16 + srow) * lda + kk + scol;
            const bf16* gb = Bt + (size_t)(n0 + chunk * 16 + srow) * ldb + kk + scol;
            __builtin_amdgcn_global_load_lds(GLOBAL_AS(ga), LDS_AS(As + chunk * 512), 16, 0, 0);
            __builtin_amdgcn_global_load_lds(GLOBAL_AS(gb), LDS_AS(Bs + chunk * 512), 16, 0, 0);
        }
        __syncthreads();
        short8 af[4], bfr[4];
#pragma unroll
        for (int i = 0; i < 4; ++i) {
            af[i]  = *(const short8*)&As[(wm + i * 16 + lrow) * 32 + lk8];
            bfr[i] = *(const short8*)&Bs[(wn + i * 16 + lrow) * 32 + lk8];
        }
#pragma unroll
        for (int i = 0; i < 4; ++i)
#pragma unroll
            for (int j = 0; j < 4; ++j)
                acc[i][j] = __builtin_amdgcn_mfma_f32_16x16x32_bf16(
                    af[i], bfr[j], acc[i][j], 0, 0, 0);
    }

    const int r4 = (lane >> 4) * 4;
#pragma unroll
    for (int i = 0; i < 4; ++i) {
#pragma unroll
        for (int r = 0; r < 4; ++r) {
            int grow = m0 + wm + i * 16 + r4 + r;
            if (OUTF32 && grow >= Mvalid) continue;
#pragma unroll
            for (int j = 0; j < 4; ++j) {
                int gcol = n0 + wn + j * 16 + lrow;
                float v  = acc[i][j][r] + bias[gcol];
                if (do_relu) v = fmaxf(v, 0.0f);
                if (OUTF32)
                    ((float*)Cv)[(size_t)grow * ldc + gcol] = v;
                else
                    ((bf16*)Cv)[(size_t)grow * ldc + gcol] = __float2bfloat16(v);
            }
        }
    }
}

// ---------------------------------------------------------------------------
// Attention v4: one block per (bt, h), 512 threads (8 waves). ZERO main-loop
// barriers: wave w independently owns row-tiles w, w+8, w+16. K resident
// [336][72], V resident transposed [64][354] (one staging barrier). Scores
// and softmax fully in registers (f[22] f32x4, unrolled constant indices;
// per-row reduce via shfl_xor 1/2/4/8 within the 16-lane D-layout group).
// PV: P transposed through a per-wave LDS chunk (same-wave ds write->read,
// lgkmcnt only). LDS = 104 KB.
#define KS_LD  72
#define VT_LD  354
__global__ __launch_bounds__(512) void attn_kernel(
    bf16* __restrict__ qkv, float* __restrict__ attn_out)
{
    __shared__ alignas(16) bf16 Ks[336 * KS_LD];        // 48384 B
    __shared__ alignas(16) bf16 Vt[64 * VT_LD + 32];    // 45376 B
    __shared__ alignas(16) bf16 ptile[8][16 * 40];      // 10240 B
    const int t = threadIdx.x, lane = t & 63, w = t >> 6;
    const int h = blockIdx.x & 7, bt = blockIdx.x >> 3;
    const size_t rowbase = (size_t)bt * N_TOK;
    const int lrow = lane & 15, lk8 = (lane >> 4) * 8;
    const int r4 = (lane >> 4) * 4;
    const int b = bt / 12, tt2 = bt % 12;
    const size_t hb_base = (((size_t)(h * 8 + b)) * 12 + tt2) * N_TOK;

    // ---- stage K (rows 0..335, zero-padded)
    for (int task = t; task < 336 * 8; task += 512) {
        int m = task >> 3, e0 = (task & 7) << 3;
        short8 v = {0, 0, 0, 0, 0, 0, 0, 0};
        if (m < N_TOK)
            v = *(const short8*)(qkv + (rowbase + m) * QKV_LD + 512 + h * 64 + e0);
        *(short8*)&Ks[m * KS_LD + e0] = v;
    }
    // ---- stage V transposed (cols 0..351, zero-padded)
    for (int task = t; task < 352 * 8; task += 512) {
        int m = task >> 3, e0 = (task & 7) << 3;
        short8 v = {0, 0, 0, 0, 0, 0, 0, 0};
        if (m < N_TOK)
            v = *(const short8*)(qkv + (rowbase + m) * QKV_LD + 1024 + h * 64 + e0);
#pragma unroll
        for (int j = 0; j < 8; ++j)
            Vt[(e0 + j) * VT_LD + m] = ((bf16*)&v)[j];
    }
    __syncthreads();   // the only block-wide barrier

    for (int it = 0; it < 3; ++it) {
        const int tile = w + it * 8;          // wave-uniform
        if (tile > 20) break;
        const int r0 = tile * 16;

        // Q fragments (lane's own row, clamped; dead rows' results discarded)
        int qrow = r0 + lrow; if (qrow > N_TOK - 1) qrow = N_TOK - 1;
        const bf16* qp = qkv + (rowbase + qrow) * QKV_LD + h * 64 + lk8;
        short8 qa0 = *(const short8*)(qp);
        short8 qa1 = *(const short8*)(qp + 32);

        // ---- QK^T into registers
        f32x4 f[22];
        f[21] = (f32x4){0.f, 0.f, 0.f, 0.f};
#pragma unroll
        for (int ct = 0; ct < 21; ++ct) {
            if (ct <= tile) {                 // wave-uniform branch
                f32x4 a = {0.f, 0.f, 0.f, 0.f};
                short8 kb0 = *(const short8*)&Ks[(ct * 16 + lrow) * KS_LD + lk8];
                short8 kb1 = *(const short8*)&Ks[(ct * 16 + lrow) * KS_LD + 32 + lk8];
                a = __builtin_amdgcn_mfma_f32_16x16x32_bf16(qa0, kb0, a, 0, 0, 0);
                a = __builtin_amdgcn_mfma_f32_16x16x32_bf16(qa1, kb1, a, 0, 0, 0);
                f[ct] = a;
            }
        }

        // ---- softmax in registers (row n = r0 + r4 + r; col c = ct*16+lrow)
        float mx[4] = {-1e30f, -1e30f, -1e30f, -1e30f};
        float sm[4] = {0.f, 0.f, 0.f, 0.f};
#pragma unroll
        for (int ct = 0; ct < 21; ++ct) {
            if (ct <= tile) {
                const int c = ct * 16 + lrow;
#pragma unroll
                for (int r = 0; r < 4; ++r)
                    if (c <= r0 + r4 + r) mx[r] = fmaxf(mx[r], f[ct][r]);
            }
        }
#pragma unroll
        for (int r = 0; r < 4; ++r) {
#pragma unroll
            for (int o = 1; o < 16; o <<= 1) mx[r] = fmaxf(mx[r], __shfl_xor(mx[r], o));
        }
#pragma unroll
        for (int ct = 0; ct < 21; ++ct) {
            if (ct <= tile) {
                const int c = ct * 16 + lrow;
#pragma unroll
                for (int r = 0; r < 4; ++r) {
                    float e = (c <= r0 + r4 + r)
                                  ? __expf((f[ct][r] - mx[r]) * 0.125f) : 0.f;
                    f[ct][r] = e;
                    sm[r] += e;
                }
            }
        }
#pragma unroll
        for (int r = 0; r < 4; ++r) {
#pragma unroll
            for (int o = 1; o < 16; o <<= 1) sm[r] += __shfl_xor(sm[r], o);
            sm[r] = 1.0f / sm[r];
        }
#pragma unroll
        for (int ct = 0; ct < 21; ++ct) {
            if (ct <= tile) {
#pragma unroll
                for (int r = 0; r < 4; ++r) f[ct][r] *= sm[r];
            }
        }

        // ---- attn writes (values + causal zeros), straight from registers
#pragma unroll
        for (int ct = 0; ct < 21; ++ct) {
            const int c = ct * 16 + lrow;
            if (c < N_TOK) {
#pragma unroll
                for (int r = 0; r < 4; ++r) {
                    const int n = r0 + r4 + r;
                    if (n < N_TOK) {
                        float v = (ct <= tile && c <= n) ? f[ct][r] : 0.f;
                        attn_out[(hb_base + n) * N_TOK + c] = v;
                    }
                }
            }
        }

        // ---- PV via per-wave LDS transpose chunks (no barriers)
        f32x4 acc[4] = {};
        bf16* pt = &ptile[w][0];
#pragma unroll
        for (int s = 0; s < 11; ++s) {
            if (s <= (tile >> 1)) {           // wave-uniform
#pragma unroll
                for (int half = 0; half < 2; ++half) {
                    const int ct2 = 2 * s + half;      // constant index
                    const int c = ct2 * 16 + lrow;
#pragma unroll
                    for (int r = 0; r < 4; ++r) {
                        const int n = r0 + r4 + r;
                        float v = (ct2 <= tile && c <= n) ? f[ct2][r] : 0.f;
                        pt[(r4 + r) * 40 + half * 16 + lrow] = __float2bfloat16(v);
                    }
                }
                // same-wave ds write -> read: compiler inserts lgkmcnt wait
                short8 aa = *(const short8*)&pt[lrow * 40 + lk8];
#pragma unroll
                for (int e = 0; e < 4; ++e) {
                    short8 bb = *(const short8*)&Vt[(e * 16 + lrow) * VT_LD + s * 32 + lk8];
                    acc[e] = __builtin_amdgcn_mfma_f32_16x16x32_bf16(aa, bb, acc[e], 0, 0, 0);
                }
            }
        }

        // ---- ctx write into q-slice of qkv (rows owned exclusively by this wave)
#pragma unroll
        for (int e = 0; e < 4; ++e) {
#pragma unroll
            for (int r = 0; r < 4; ++r) {
                const int n = r0 + r4 + r;
                if (n < N_TOK)
                    qkv[(rowbase + n) * QKV_LD + h * 64 + e * 16 + lrow] =
                        __float2bfloat16(acc[e][r]);
            }
        }
    }
}

// ---------------------------------------------------------------------------
extern "C" void kernel_launch(void* const* d_in, const int* in_sizes, int n_in,
                              void* d_out, int out_size, void* d_ws, size_t ws_size,
                              hipStream_t stream)
{
    const void* X   = d_in[0];
    const void* STE = d_in[1];
    const void* Wq  = d_in[2];
    const void* bq  = d_in[3];
    const void* Wk  = d_in[4];
    const void* bk  = d_in[5];
    const void* Wv  = d_in[6];
    const void* bv  = d_in[7];
    const void* W1  = d_in[8];
    const void* b1  = d_in[9];
    const void* W2  = d_in[10];
    const void* b2  = d_in[11];

    float* out0     = (float*)d_out;                              // [31200][512] f32
    float* attn_out = (float*)d_out + (size_t)M_ROWS * D_MODEL;   // [64][12][325][325] f32
    bf16*  Xc       = (bf16*)attn_out;   // scratch; overwritten by attn_kernel later

    char* ws = (char*)d_ws;
    bf16*  qkv   = (bf16*)(ws);                      // 31232*1536*2 = 95,944,704
    bf16*  BtQKV = (bf16*)(ws + 95944704);           //  3,145,728
    bf16*  W1T   = (bf16*)(ws + 99090432);           //    524,288
    bf16*  W2T   = (bf16*)(ws + 99614720);           //    524,288
    float* biasQ = (float*)(ws + 100139008);         //      6,144
    float* b1f   = (float*)(ws + 100145152);         //      2,048
    float* b2f   = (float*)(ws + 100147200);         //      2,048
    int*   flag  = (int*)(ws + 100149248);           //          4
    bf16*  hbuf  = qkv + 512;                        // FFN hidden aliases k-slice

    init_flag<<<1, 64, 0, stream>>>(flag);
    detect_dtype<<<64, 256, 0, stream>>>((const unsigned short*)X, flag);

    transpose_w_tiled<<<dim3(16, 32), 256, 0, stream>>>(Wq, BtQKV, 1024, 512, flag);
    transpose_w_tiled<<<dim3(16, 32), 256, 0, stream>>>(Wk, BtQKV + 512 * 1024, 1024, 512, flag);
    transpose_w_tiled<<<dim3(16, 32), 256, 0, stream>>>(Wv, BtQKV + 1024 * 1024, 1024, 512, flag);
    transpose_w_tiled<<<dim3(16, 16), 256, 0, stream>>>(W1, W1T, 512, 512, flag);
    transpose_w_tiled<<<dim3(16, 16), 256, 0, stream>>>(W2, W2T, 512, 512, flag);
    prep_bias<<<2, 256, 0, stream>>>(bq, bk, bv, b1, b2, biasQ, b1f, b2f, flag);

    // concat(X,STE) -> bf16 Xc [31232][1024]
    concat_cast<<<(M_PAD * 128) / 256, 256, 0, stream>>>(X, STE, Xc, flag);

    // QKV projection: Xc[31232,1024] @ BtQKV^T -> qkv (+bias, relu)
    gemm_lds<0><<<244 * 12, 256, 0, stream>>>(
        Xc, 1024, BtQKV, 1024, biasQ, qkv, M_PAD, 1024, QKV_LD, 1, 244);

    // attention (ctx -> q-slice of qkv; attn -> f32 d_out region, overwrites Xc)
    attn_kernel<<<768, 512, 0, stream>>>(qkv, attn_out);

    // FFN1: relu(ctx @ W1 + b1) -> hbuf (k-slice of qkv)
    gemm_lds<0><<<244 * 4, 256, 0, stream>>>(
        qkv, QKV_LD, W1T, 512, b1f, hbuf, M_PAD, 512, QKV_LD, 1, 244);

    // FFN2: hbuf @ W2 + b2 -> out0 (f32, guarded at M_ROWS)
    gemm_lds<1><<<244 * 4, 256, 0, stream>>>(
        hbuf, QKV_LD, W2T, 512, b2f, out0, M_ROWS, 512, D_MODEL, 0, 244);
}

// Round 10
// 446.171 us; speedup vs baseline: 1.6320x; 1.0143x over previous
//
#include <hip/hip_runtime.h>
#include <hip/hip_bf16.h>

typedef __hip_bfloat16 bf16;
using f32x4  = __attribute__((ext_vector_type(4))) float;
using short8 = __attribute__((ext_vector_type(8))) short;

// B=8, T=12, N=325, K=8 heads, d=64, D=512, BT=96, M=31200 (padded 31232)
#define M_ROWS   31200
#define M_PAD    31232
#define N_TOK    325
#define D_MODEL  512
#define QKV_LD   1536

#define GLOBAL_AS(p) ((const __attribute__((address_space(1))) unsigned int*)(p))
#define LDS_AS(p)    ((__attribute__((address_space(3))) unsigned int*)(p))

// ---------------------------------------------------------------------------
// dtype detection: device inputs are either f32 or bf16 (flag=1 -> f32).
__global__ void init_flag(int* flag) { if (threadIdx.x == 0) *flag = 0; }

__global__ void detect_dtype(const unsigned short* __restrict__ x, int* flag)
{
    int i = blockIdx.x * 256 + threadIdx.x;   // 64 blocks * 256 = 16384 halves
    unsigned short h = x[i];
    int e = (h >> 7) & 0xFF;
    if (e >= 135) atomicOr(flag, 1);
}

__device__ __forceinline__ float load_in(const void* p, size_t i, bool f32)
{
    return f32 ? ((const float*)p)[i] : __bfloat162float(((const bf16*)p)[i]);
}

// ---------------------------------------------------------------------------
// concat(X,STE) -> bf16 Xc[31232][1024]; rows >= 31200 zeroed.
__global__ void concat_cast(const void* __restrict__ X, const void* __restrict__ STE,
                            bf16* __restrict__ Xc, const int* __restrict__ flag)
{
    const bool f32 = (*flag != 0);
    int idx = blockIdx.x * 256 + threadIdx.x;       // M_PAD*128 tasks of 8 elems
    int r = idx >> 7, c8 = (idx & 127) << 3;
    short8 v = {0, 0, 0, 0, 0, 0, 0, 0};
    if (r < M_ROWS) {
        const void* src = (c8 < 512) ? X : STE;
        int cc = c8 & 511;
        if (f32) {
            const float* s = (const float*)src + (size_t)r * 512 + cc;
            float4 a = *(const float4*)s;
            float4 b = *(const float4*)(s + 4);
            ((bf16*)&v)[0] = __float2bfloat16(a.x); ((bf16*)&v)[1] = __float2bfloat16(a.y);
            ((bf16*)&v)[2] = __float2bfloat16(a.z); ((bf16*)&v)[3] = __float2bfloat16(a.w);
            ((bf16*)&v)[4] = __float2bfloat16(b.x); ((bf16*)&v)[5] = __float2bfloat16(b.y);
            ((bf16*)&v)[6] = __float2bfloat16(b.z); ((bf16*)&v)[7] = __float2bfloat16(b.w);
        } else {
            v = *(const short8*)((const bf16*)src + (size_t)r * 512 + cc);
        }
    }
    *(short8*)&Xc[(size_t)r * 1024 + c8] = v;
}

// ---------------------------------------------------------------------------
// tiled transpose: src [krows][ncols] -> dst [ncols][krows] bf16 (coalesced)
__global__ void transpose_w_tiled(const void* __restrict__ src, bf16* __restrict__ dst,
                                  int krows, int ncols, const int* __restrict__ flag)
{
    __shared__ float tile[32][33];
    const bool f32 = (*flag != 0);
    const int kt = blockIdx.y * 32, nt = blockIdx.x * 32;
    const int tx = threadIdx.x & 31, ty = threadIdx.x >> 5;   // 32 x 8
#pragma unroll
    for (int r = 0; r < 32; r += 8)
        tile[ty + r][tx] = load_in(src, (size_t)(kt + ty + r) * ncols + (nt + tx), f32);
    __syncthreads();
#pragma unroll
    for (int r = 0; r < 32; r += 8)
        dst[(size_t)(nt + ty + r) * krows + (kt + tx)] = __float2bfloat16(tile[tx][ty + r]);
}

__global__ void prep_bias(const void* __restrict__ bq, const void* __restrict__ bk,
                          const void* __restrict__ bv, const void* __restrict__ b1,
                          const void* __restrict__ b2,
                          float* __restrict__ biasQKV, float* __restrict__ b1f,
                          float* __restrict__ b2f, const int* __restrict__ flag)
{
    const bool f32 = (*flag != 0);
    int i = blockIdx.x * 256 + threadIdx.x;
    if (i < 512) {
        biasQKV[i]        = load_in(bq, i, f32);
        biasQKV[512 + i]  = load_in(bk, i, f32);
        biasQKV[1024 + i] = load_in(bv, i, f32);
        b1f[i] = load_in(b1, i, f32);
        b2f[i] = load_in(b2, i, f32);
    }
}

// ---------------------------------------------------------------------------
// m97-style 128x128 GEMM, BK=64 via dual [128][32] buffers: same verified
// staging (wave-uniform dest + lane*16, linear both sides) and same 64B-row
// read pattern as the round-8/9 BK=32 version, but HALF the barrier/vmcnt
// drains (m233: drain overhead dominates the 2-phase loop). 32KB LDS.
template<int OUTF32>
__global__ __launch_bounds__(256) void gemm_lds(
    const bf16* __restrict__ A, int lda,
    const bf16* __restrict__ Bt, int ldb,
    const float* __restrict__ bias, void* __restrict__ Cv,
    int Mvalid, int Kdim, int ldc, int do_relu, int nbx)
{
    __shared__ alignas(16) bf16 As0[128 * 32];
    __shared__ alignas(16) bf16 As1[128 * 32];
    __shared__ alignas(16) bf16 Bs0[128 * 32];
    __shared__ alignas(16) bf16 Bs1[128 * 32];
    const int cpx = gridDim.x >> 3;
    const int swz = (blockIdx.x & 7) * cpx + (blockIdx.x >> 3);
    const int m0 = (swz % nbx) * 128;
    const int n0 = (swz / nbx) * 128;
    const int t = threadIdx.x, wave = t >> 6, lane = t & 63;
    const int wm = (wave >> 1) * 64, wn = (wave & 1) * 64;
    const int lrow = lane & 15, lk8 = (lane >> 4) * 8;
    const int srow = lane >> 2, scol = (lane & 3) << 3;
    f32x4 acc[4][4] = {};
    const int nk = Kdim >> 6;                // BK = 64

    for (int ks = 0; ks < nk; ++ks) {
        const int kk = ks << 6;
        __syncthreads();   // previous tile's LDS reads complete
#pragma unroll
        for (int c = 0; c < 2; ++c) {
            const int chunk = wave * 2 + c;            // 0..7, 16 rows each
            const bf16* ga = A  + (size_t)(m0 + chunk * 16 + srow) * lda + kk + scol;
            const bf16* gb = Bt + (size_t)(n0 + chunk * 16 + srow) * ldb + kk + scol;
            __builtin_amdgcn_global_load_lds(GLOBAL_AS(ga),      LDS_AS(As0 + chunk * 512), 16, 0, 0);
            __builtin_amdgcn_global_load_lds(GLOBAL_AS(ga + 32), LDS_AS(As1 + chunk * 512), 16, 0, 0);
            __builtin_amdgcn_global_load_lds(GLOBAL_AS(gb),      LDS_AS(Bs0 + chunk * 512), 16, 0, 0);
            __builtin_amdgcn_global_load_lds(GLOBAL_AS(gb + 32), LDS_AS(Bs1 + chunk * 512), 16, 0, 0);
        }
        __syncthreads();   // staging complete (compiler drains vmcnt)
        short8 af[4], bfr[4];
        // k half 0
#pragma unroll
        for (int i = 0; i < 4; ++i) {
            af[i]  = *(const short8*)&As0[(wm + i * 16 + lrow) * 32 + lk8];
            bfr[i] = *(const short8*)&Bs0[(wn + i * 16 + lrow) * 32 + lk8];
        }
#pragma unroll
        for (int i = 0; i < 4; ++i)
#pragma unroll
            for (int j = 0; j < 4; ++j)
                acc[i][j] = __builtin_amdgcn_mfma_f32_16x16x32_bf16(
                    af[i], bfr[j], acc[i][j], 0, 0, 0);
        // k half 1
#pragma unroll
        for (int i = 0; i < 4; ++i) {
            af[i]  = *(const short8*)&As1[(wm + i * 16 + lrow) * 32 + lk8];
            bfr[i] = *(const short8*)&Bs1[(wn + i * 16 + lrow) * 32 + lk8];
        }
#pragma unroll
        for (int i = 0; i < 4; ++i)
#pragma unroll
            for (int j = 0; j < 4; ++j)
                acc[i][j] = __builtin_amdgcn_mfma_f32_16x16x32_bf16(
                    af[i], bfr[j], acc[i][j], 0, 0, 0);
    }

    const int r4 = (lane >> 4) * 4;
#pragma unroll
    for (int i = 0; i < 4; ++i) {
#pragma unroll
        for (int r = 0; r < 4; ++r) {
            int grow = m0 + wm + i * 16 + r4 + r;
            if (OUTF32 && grow >= Mvalid) continue;
#pragma unroll
            for (int j = 0; j < 4; ++j) {
                int gcol = n0 + wn + j * 16 + lrow;
                float v  = acc[i][j][r] + bias[gcol];
                if (do_relu) v = fmaxf(v, 0.0f);
                if (OUTF32)
                    ((float*)Cv)[(size_t)grow * ldc + gcol] = v;
                else
                    ((bf16*)Cv)[(size_t)grow * ldc + gcol] = __float2bfloat16(v);
            }
        }
    }
}

// ---------------------------------------------------------------------------
// Attention v4 (verified round 9, unchanged): one block per (bt, h), 512
// threads (8 waves), zero main-loop barriers; wave w owns tiles w, w+8, w+16.
// K resident [336][72], V transposed [64][354]; scores+softmax in registers;
// PV via per-wave LDS transpose chunk. LDS = 104 KB.
#define KS_LD  72
#define VT_LD  354
__global__ __launch_bounds__(512) void attn_kernel(
    bf16* __restrict__ qkv, float* __restrict__ attn_out)
{
    __shared__ alignas(16) bf16 Ks[336 * KS_LD];        // 48384 B
    __shared__ alignas(16) bf16 Vt[64 * VT_LD + 32];    // 45376 B
    __shared__ alignas(16) bf16 ptile[8][16 * 40];      // 10240 B
    const int t = threadIdx.x, lane = t & 63, w = t >> 6;
    const int h = blockIdx.x & 7, bt = blockIdx.x >> 3;
    const size_t rowbase = (size_t)bt * N_TOK;
    const int lrow = lane & 15, lk8 = (lane >> 4) * 8;
    const int r4 = (lane >> 4) * 4;
    const int b = bt / 12, tt2 = bt % 12;
    const size_t hb_base = (((size_t)(h * 8 + b)) * 12 + tt2) * N_TOK;

    for (int task = t; task < 336 * 8; task += 512) {
        int m = task >> 3, e0 = (task & 7) << 3;
        short8 v = {0, 0, 0, 0, 0, 0, 0, 0};
        if (m < N_TOK)
            v = *(const short8*)(qkv + (rowbase + m) * QKV_LD + 512 + h * 64 + e0);
        *(short8*)&Ks[m * KS_LD + e0] = v;
    }
    for (int task = t; task < 352 * 8; task += 512) {
        int m = task >> 3, e0 = (task & 7) << 3;
        short8 v = {0, 0, 0, 0, 0, 0, 0, 0};
        if (m < N_TOK)
            v = *(const short8*)(qkv + (rowbase + m) * QKV_LD + 1024 + h * 64 + e0);
#pragma unroll
        for (int j = 0; j < 8; ++j)
            Vt[(e0 + j) * VT_LD + m] = ((bf16*)&v)[j];
    }
    __syncthreads();   // the only block-wide barrier

    for (int it = 0; it < 3; ++it) {
        const int tile = w + it * 8;          // wave-uniform
        if (tile > 20) break;
        const int r0 = tile * 16;

        int qrow = r0 + lrow; if (qrow > N_TOK - 1) qrow = N_TOK - 1;
        const bf16* qp = qkv + (rowbase + qrow) * QKV_LD + h * 64 + lk8;
        short8 qa0 = *(const short8*)(qp);
        short8 qa1 = *(const short8*)(qp + 32);

        f32x4 f[22];
        f[21] = (f32x4){0.f, 0.f, 0.f, 0.f};
#pragma unroll
        for (int ct = 0; ct < 21; ++ct) {
            if (ct <= tile) {                 // wave-uniform branch
                f32x4 a = {0.f, 0.f, 0.f, 0.f};
                short8 kb0 = *(const short8*)&Ks[(ct * 16 + lrow) * KS_LD + lk8];
                short8 kb1 = *(const short8*)&Ks[(ct * 16 + lrow) * KS_LD + 32 + lk8];
                a = __builtin_amdgcn_mfma_f32_16x16x32_bf16(qa0, kb0, a, 0, 0, 0);
                a = __builtin_amdgcn_mfma_f32_16x16x32_bf16(qa1, kb1, a, 0, 0, 0);
                f[ct] = a;
            }
        }

        float mx[4] = {-1e30f, -1e30f, -1e30f, -1e30f};
        float sm[4] = {0.f, 0.f, 0.f, 0.f};
#pragma unroll
        for (int ct = 0; ct < 21; ++ct) {
            if (ct <= tile) {
                const int c = ct * 16 + lrow;
#pragma unroll
                for (int r = 0; r < 4; ++r)
                    if (c <= r0 + r4 + r) mx[r] = fmaxf(mx[r], f[ct][r]);
            }
        }
#pragma unroll
        for (int r = 0; r < 4; ++r) {
#pragma unroll
            for (int o = 1; o < 16; o <<= 1) mx[r] = fmaxf(mx[r], __shfl_xor(mx[r], o));
        }
#pragma unroll
        for (int ct = 0; ct < 21; ++ct) {
            if (ct <= tile) {
                const int c = ct * 16 + lrow;
#pragma unroll
                for (int r = 0; r < 4; ++r) {
                    float e = (c <= r0 + r4 + r)
                                  ? __expf((f[ct][r] - mx[r]) * 0.125f) : 0.f;
                    f[ct][r] = e;
                    sm[r] += e;
                }
            }
        }
#pragma unroll
        for (int r = 0; r < 4; ++r) {
#pragma unroll
            for (int o = 1; o < 16; o <<= 1) sm[r] += __shfl_xor(sm[r], o);
            sm[r] = 1.0f / sm[r];
        }
#pragma unroll
        for (int ct = 0; ct < 21; ++ct) {
            if (ct <= tile) {
#pragma unroll
                for (int r = 0; r < 4; ++r) f[ct][r] *= sm[r];
            }
        }

#pragma unroll
        for (int ct = 0; ct < 21; ++ct) {
            const int c = ct * 16 + lrow;
            if (c < N_TOK) {
#pragma unroll
                for (int r = 0; r < 4; ++r) {
                    const int n = r0 + r4 + r;
                    if (n < N_TOK) {
                        float v = (ct <= tile && c <= n) ? f[ct][r] : 0.f;
                        attn_out[(hb_base + n) * N_TOK + c] = v;
                    }
                }
            }
        }

        f32x4 acc[4] = {};
        bf16* pt = &ptile[w][0];
#pragma unroll
        for (int s = 0; s < 11; ++s) {
            if (s <= (tile >> 1)) {           // wave-uniform
#pragma unroll
                for (int half = 0; half < 2; ++half) {
                    const int ct2 = 2 * s + half;
                    const int c = ct2 * 16 + lrow;
#pragma unroll
                    for (int r = 0; r < 4; ++r) {
                        const int n = r0 + r4 + r;
                        float v = (ct2 <= tile && c <= n) ? f[ct2][r] : 0.f;
                        pt[(r4 + r) * 40 + half * 16 + lrow] = __float2bfloat16(v);
                    }
                }
                short8 aa = *(const short8*)&pt[lrow * 40 + lk8];
#pragma unroll
                for (int e = 0; e < 4; ++e) {
                    short8 bb = *(const short8*)&Vt[(e * 16 + lrow) * VT_LD + s * 32 + lk8];
                    acc[e] = __builtin_amdgcn_mfma_f32_16x16x32_bf16(aa, bb, acc[e], 0, 0, 0);
                }
            }
        }

#pragma unroll
        for (int e = 0; e < 4; ++e) {
#pragma unroll
            for (int r = 0; r < 4; ++r) {
                const int n = r0 + r4 + r;
                if (n < N_TOK)
                    qkv[(rowbase + n) * QKV_LD + h * 64 + e * 16 + lrow] =
                        __float2bfloat16(acc[e][r]);
            }
        }
    }
}

// ---------------------------------------------------------------------------
extern "C" void kernel_launch(void* const* d_in, const int* in_sizes, int n_in,
                              void* d_out, int out_size, void* d_ws, size_t ws_size,
                              hipStream_t stream)
{
    const void* X   = d_in[0];
    const void* STE = d_in[1];
    const void* Wq  = d_in[2];
    const void* bq  = d_in[3];
    const void* Wk  = d_in[4];
    const void* bk  = d_in[5];
    const void* Wv  = d_in[6];
    const void* bv  = d_in[7];
    const void* W1  = d_in[8];
    const void* b1  = d_in[9];
    const void* W2  = d_in[10];
    const void* b2  = d_in[11];

    float* out0     = (float*)d_out;                              // [31200][512] f32
    float* attn_out = (float*)d_out + (size_t)M_ROWS * D_MODEL;   // [64][12][325][325] f32
    bf16*  Xc       = (bf16*)attn_out;   // scratch; overwritten by attn_kernel later

    char* ws = (char*)d_ws;
    bf16*  qkv   = (bf16*)(ws);                      // 31232*1536*2 = 95,944,704
    bf16*  BtQKV = (bf16*)(ws + 95944704);           //  3,145,728
    bf16*  W1T   = (bf16*)(ws + 99090432);           //    524,288
    bf16*  W2T   = (bf16*)(ws + 99614720);           //    524,288
    float* biasQ = (float*)(ws + 100139008);         //      6,144
    float* b1f   = (float*)(ws + 100145152);         //      2,048
    float* b2f   = (float*)(ws + 100147200);         //      2,048
    int*   flag  = (int*)(ws + 100149248);           //          4
    bf16*  hbuf  = qkv + 512;                        // FFN hidden aliases k-slice

    init_flag<<<1, 64, 0, stream>>>(flag);
    detect_dtype<<<64, 256, 0, stream>>>((const unsigned short*)X, flag);

    transpose_w_tiled<<<dim3(16, 32), 256, 0, stream>>>(Wq, BtQKV, 1024, 512, flag);
    transpose_w_tiled<<<dim3(16, 32), 256, 0, stream>>>(Wk, BtQKV + 512 * 1024, 1024, 512, flag);
    transpose_w_tiled<<<dim3(16, 32), 256, 0, stream>>>(Wv, BtQKV + 1024 * 1024, 1024, 512, flag);
    transpose_w_tiled<<<dim3(16, 16), 256, 0, stream>>>(W1, W1T, 512, 512, flag);
    transpose_w_tiled<<<dim3(16, 16), 256, 0, stream>>>(W2, W2T, 512, 512, flag);
    prep_bias<<<2, 256, 0, stream>>>(bq, bk, bv, b1, b2, biasQ, b1f, b2f, flag);

    // concat(X,STE) -> bf16 Xc [31232][1024]
    concat_cast<<<(M_PAD * 128) / 256, 256, 0, stream>>>(X, STE, Xc, flag);

    // QKV projection: Xc[31232,1024] @ BtQKV^T -> qkv (+bias, relu)
    gemm_lds<0><<<244 * 12, 256, 0, stream>>>(
        Xc, 1024, BtQKV, 1024, biasQ, qkv, M_PAD, 1024, QKV_LD, 1, 244);

    // attention (ctx -> q-slice of qkv; attn -> f32 d_out region, overwrites Xc)
    attn_kernel<<<768, 512, 0, stream>>>(qkv, attn_out);

    // FFN1: relu(ctx @ W1 + b1) -> hbuf (k-slice of qkv)
    gemm_lds<0><<<244 * 4, 256, 0, stream>>>(
        qkv, QKV_LD, W1T, 512, b1f, hbuf, M_PAD, 512, QKV_LD, 1, 244);

    // FFN2: hbuf @ W2 + b2 -> out0 (f32, guarded at M_ROWS)
    gemm_lds<1><<<244 * 4, 256, 0, stream>>>(
        hbuf, QKV_LD, W2T, 512, b2f, out0, M_ROWS, 512, D_MODEL, 0, 244);
}

// Round 11
// 419.755 us; speedup vs baseline: 1.7347x; 1.0629x over previous
//
#include <hip/hip_runtime.h>
#include <hip/hip_bf16.h>

typedef __hip_bfloat16 bf16;
using f32x4  = __attribute__((ext_vector_type(4))) float;
using short8 = __attribute__((ext_vector_type(8))) short;

// B=8, T=12, N=325, K=8 heads, d=64, D=512, BT=96, M=31200 (padded 31232)
#define M_ROWS   31200
#define M_PAD    31232
#define N_TOK    325
#define D_MODEL  512
#define QKV_LD   1536

#define GLOBAL_AS(p) ((const __attribute__((address_space(1))) unsigned int*)(p))
#define LDS_AS(p)    ((__attribute__((address_space(3))) unsigned int*)(p))

// ---------------------------------------------------------------------------
// dtype detection: device inputs are either f32 or bf16 (flag=1 -> f32).
__global__ void init_flag(int* flag) { if (threadIdx.x == 0) *flag = 0; }

__global__ void detect_dtype(const unsigned short* __restrict__ x, int* flag)
{
    int i = blockIdx.x * 256 + threadIdx.x;   // 64 blocks * 256 = 16384 halves
    unsigned short h = x[i];
    int e = (h >> 7) & 0xFF;
    if (e >= 135) atomicOr(flag, 1);
}

__device__ __forceinline__ float load_in(const void* p, size_t i, bool f32)
{
    return f32 ? ((const float*)p)[i] : __bfloat162float(((const bf16*)p)[i]);
}

// ---------------------------------------------------------------------------
// concat(X,STE) -> bf16 Xc[31232][1024]; rows >= 31200 zeroed.
__global__ void concat_cast(const void* __restrict__ X, const void* __restrict__ STE,
                            bf16* __restrict__ Xc, const int* __restrict__ flag)
{
    const bool f32 = (*flag != 0);
    int idx = blockIdx.x * 256 + threadIdx.x;       // M_PAD*128 tasks of 8 elems
    int r = idx >> 7, c8 = (idx & 127) << 3;
    short8 v = {0, 0, 0, 0, 0, 0, 0, 0};
    if (r < M_ROWS) {
        const void* src = (c8 < 512) ? X : STE;
        int cc = c8 & 511;
        if (f32) {
            const float* s = (const float*)src + (size_t)r * 512 + cc;
            float4 a = *(const float4*)s;
            float4 b = *(const float4*)(s + 4);
            ((bf16*)&v)[0] = __float2bfloat16(a.x); ((bf16*)&v)[1] = __float2bfloat16(a.y);
            ((bf16*)&v)[2] = __float2bfloat16(a.z); ((bf16*)&v)[3] = __float2bfloat16(a.w);
            ((bf16*)&v)[4] = __float2bfloat16(b.x); ((bf16*)&v)[5] = __float2bfloat16(b.y);
            ((bf16*)&v)[6] = __float2bfloat16(b.z); ((bf16*)&v)[7] = __float2bfloat16(b.w);
        } else {
            v = *(const short8*)((const bf16*)src + (size_t)r * 512 + cc);
        }
    }
    *(short8*)&Xc[(size_t)r * 1024 + c8] = v;
}

// ---------------------------------------------------------------------------
// tiled transpose: src [krows][ncols] -> dst [ncols][krows] bf16 (coalesced)
__global__ void transpose_w_tiled(const void* __restrict__ src, bf16* __restrict__ dst,
                                  int krows, int ncols, const int* __restrict__ flag)
{
    __shared__ float tile[32][33];
    const bool f32 = (*flag != 0);
    const int kt = blockIdx.y * 32, nt = blockIdx.x * 32;
    const int tx = threadIdx.x & 31, ty = threadIdx.x >> 5;   // 32 x 8
#pragma unroll
    for (int r = 0; r < 32; r += 8)
        tile[ty + r][tx] = load_in(src, (size_t)(kt + ty + r) * ncols + (nt + tx), f32);
    __syncthreads();
#pragma unroll
    for (int r = 0; r < 32; r += 8)
        dst[(size_t)(nt + ty + r) * krows + (kt + tx)] = __float2bfloat16(tile[tx][ty + r]);
}

__global__ void prep_bias(const void* __restrict__ bq, const void* __restrict__ bk,
                          const void* __restrict__ bv, const void* __restrict__ b1,
                          const void* __restrict__ b2,
                          float* __restrict__ biasQKV, float* __restrict__ b1f,
                          float* __restrict__ b2f, const int* __restrict__ flag)
{
    const bool f32 = (*flag != 0);
    int i = blockIdx.x * 256 + threadIdx.x;
    if (i < 512) {
        biasQKV[i]        = load_in(bq, i, f32);
        biasQKV[512 + i]  = load_in(bk, i, f32);
        biasQKV[1024 + i] = load_in(bv, i, f32);
        b1f[i] = load_in(b1, i, f32);
        b2f[i] = load_in(b2, i, f32);
    }
}

// ---------------------------------------------------------------------------
// m97-style 128x128 GEMM, BK=64 dual buffers. LOOP-ORDER FIX (round 11):
// m0 = swz / nby (n fastest) so consecutive blocks on an XCD reuse one A-band
// across all n-tiles via L2; previously m-fastest re-streamed the whole A
// matrix once per n-band (round-7 counters: FETCH 517MB vs ~100MB ideal).
template<int OUTF32>
__global__ __launch_bounds__(256) void gemm_lds(
    const bf16* __restrict__ A, int lda,
    const bf16* __restrict__ Bt, int ldb,
    const float* __restrict__ bias, void* __restrict__ Cv,
    int Mvalid, int Kdim, int ldc, int do_relu, int nby)
{
    __shared__ alignas(16) bf16 As0[128 * 32];
    __shared__ alignas(16) bf16 As1[128 * 32];
    __shared__ alignas(16) bf16 Bs0[128 * 32];
    __shared__ alignas(16) bf16 Bs1[128 * 32];
    const int cpx = gridDim.x >> 3;
    const int swz = (blockIdx.x & 7) * cpx + (blockIdx.x >> 3);
    const int m0 = (swz / nby) * 128;
    const int n0 = (swz % nby) * 128;
    const int t = threadIdx.x, wave = t >> 6, lane = t & 63;
    const int wm = (wave >> 1) * 64, wn = (wave & 1) * 64;
    const int lrow = lane & 15, lk8 = (lane >> 4) * 8;
    const int srow = lane >> 2, scol = (lane & 3) << 3;
    f32x4 acc[4][4] = {};
    const int nk = Kdim >> 6;                // BK = 64

    for (int ks = 0; ks < nk; ++ks) {
        const int kk = ks << 6;
        __syncthreads();   // previous tile's LDS reads complete
#pragma unroll
        for (int c = 0; c < 2; ++c) {
            const int chunk = wave * 2 + c;            // 0..7, 16 rows each
            const bf16* ga = A  + (size_t)(m0 + chunk * 16 + srow) * lda + kk + scol;
            const bf16* gb = Bt + (size_t)(n0 + chunk * 16 + srow) * ldb + kk + scol;
            __builtin_amdgcn_global_load_lds(GLOBAL_AS(ga),      LDS_AS(As0 + chunk * 512), 16, 0, 0);
            __builtin_amdgcn_global_load_lds(GLOBAL_AS(ga + 32), LDS_AS(As1 + chunk * 512), 16, 0, 0);
            __builtin_amdgcn_global_load_lds(GLOBAL_AS(gb),      LDS_AS(Bs0 + chunk * 512), 16, 0, 0);
            __builtin_amdgcn_global_load_lds(GLOBAL_AS(gb + 32), LDS_AS(Bs1 + chunk * 512), 16, 0, 0);
        }
        __syncthreads();   // staging complete (compiler drains vmcnt)
        short8 af[4], bfr[4];
        // k half 0
#pragma unroll
        for (int i = 0; i < 4; ++i) {
            af[i]  = *(const short8*)&As0[(wm + i * 16 + lrow) * 32 + lk8];
            bfr[i] = *(const short8*)&Bs0[(wn + i * 16 + lrow) * 32 + lk8];
        }
#pragma unroll
        for (int i = 0; i < 4; ++i)
#pragma unroll
            for (int j = 0; j < 4; ++j)
                acc[i][j] = __builtin_amdgcn_mfma_f32_16x16x32_bf16(
                    af[i], bfr[j], acc[i][j], 0, 0, 0);
        // k half 1
#pragma unroll
        for (int i = 0; i < 4; ++i) {
            af[i]  = *(const short8*)&As1[(wm + i * 16 + lrow) * 32 + lk8];
            bfr[i] = *(const short8*)&Bs1[(wn + i * 16 + lrow) * 32 + lk8];
        }
#pragma unroll
        for (int i = 0; i < 4; ++i)
#pragma unroll
            for (int j = 0; j < 4; ++j)
                acc[i][j] = __builtin_amdgcn_mfma_f32_16x16x32_bf16(
                    af[i], bfr[j], acc[i][j], 0, 0, 0);
    }

    const int r4 = (lane >> 4) * 4;
#pragma unroll
    for (int i = 0; i < 4; ++i) {
#pragma unroll
        for (int r = 0; r < 4; ++r) {
            int grow = m0 + wm + i * 16 + r4 + r;
            if (OUTF32 && grow >= Mvalid) continue;
#pragma unroll
            for (int j = 0; j < 4; ++j) {
                int gcol = n0 + wn + j * 16 + lrow;
                float v  = acc[i][j][r] + bias[gcol];
                if (do_relu) v = fmaxf(v, 0.0f);
                if (OUTF32)
                    ((float*)Cv)[(size_t)grow * ldc + gcol] = v;
                else
                    ((bf16*)Cv)[(size_t)grow * ldc + gcol] = __float2bfloat16(v);
            }
        }
    }
}

// ---------------------------------------------------------------------------
// Attention v4.1: as round 9/10 (zero main-loop barriers, K resident,
// V transposed, in-register softmax) + balanced third pass: it==2 assigns
// tile = 20-w to waves 0-4 (was w+16), cutting the slowest wave's
// triangular work from 36 to 32 units. Per-wave exclusivity preserved.
#define KS_LD  72
#define VT_LD  354
__global__ __launch_bounds__(512) void attn_kernel(
    bf16* __restrict__ qkv, float* __restrict__ attn_out)
{
    __shared__ alignas(16) bf16 Ks[336 * KS_LD];        // 48384 B
    __shared__ alignas(16) bf16 Vt[64 * VT_LD + 32];    // 45376 B
    __shared__ alignas(16) bf16 ptile[8][16 * 40];      // 10240 B
    const int t = threadIdx.x, lane = t & 63, w = t >> 6;
    const int h = blockIdx.x & 7, bt = blockIdx.x >> 3;
    const size_t rowbase = (size_t)bt * N_TOK;
    const int lrow = lane & 15, lk8 = (lane >> 4) * 8;
    const int r4 = (lane >> 4) * 4;
    const int b = bt / 12, tt2 = bt % 12;
    const size_t hb_base = (((size_t)(h * 8 + b)) * 12 + tt2) * N_TOK;

    for (int task = t; task < 336 * 8; task += 512) {
        int m = task >> 3, e0 = (task & 7) << 3;
        short8 v = {0, 0, 0, 0, 0, 0, 0, 0};
        if (m < N_TOK)
            v = *(const short8*)(qkv + (rowbase + m) * QKV_LD + 512 + h * 64 + e0);
        *(short8*)&Ks[m * KS_LD + e0] = v;
    }
    for (int task = t; task < 352 * 8; task += 512) {
        int m = task >> 3, e0 = (task & 7) << 3;
        short8 v = {0, 0, 0, 0, 0, 0, 0, 0};
        if (m < N_TOK)
            v = *(const short8*)(qkv + (rowbase + m) * QKV_LD + 1024 + h * 64 + e0);
#pragma unroll
        for (int j = 0; j < 8; ++j)
            Vt[(e0 + j) * VT_LD + m] = ((bf16*)&v)[j];
    }
    __syncthreads();   // the only block-wide barrier

    for (int it = 0; it < 3; ++it) {
        if (it == 2 && w > 4) break;
        const int tile = (it < 2) ? (w + it * 8) : (20 - w);   // wave-uniform
        const int r0 = tile * 16;

        int qrow = r0 + lrow; if (qrow > N_TOK - 1) qrow = N_TOK - 1;
        const bf16* qp = qkv + (rowbase + qrow) * QKV_LD + h * 64 + lk8;
        short8 qa0 = *(const short8*)(qp);
        short8 qa1 = *(const short8*)(qp + 32);

        f32x4 f[22];
        f[21] = (f32x4){0.f, 0.f, 0.f, 0.f};
#pragma unroll
        for (int ct = 0; ct < 21; ++ct) {
            if (ct <= tile) {                 // wave-uniform branch
                f32x4 a = {0.f, 0.f, 0.f, 0.f};
                short8 kb0 = *(const short8*)&Ks[(ct * 16 + lrow) * KS_LD + lk8];
                short8 kb1 = *(const short8*)&Ks[(ct * 16 + lrow) * KS_LD + 32 + lk8];
                a = __builtin_amdgcn_mfma_f32_16x16x32_bf16(qa0, kb0, a, 0, 0, 0);
                a = __builtin_amdgcn_mfma_f32_16x16x32_bf16(qa1, kb1, a, 0, 0, 0);
                f[ct] = a;
            }
        }

        float mx[4] = {-1e30f, -1e30f, -1e30f, -1e30f};
        float sm[4] = {0.f, 0.f, 0.f, 0.f};
#pragma unroll
        for (int ct = 0; ct < 21; ++ct) {
            if (ct <= tile) {
                const int c = ct * 16 + lrow;
#pragma unroll
                for (int r = 0; r < 4; ++r)
                    if (c <= r0 + r4 + r) mx[r] = fmaxf(mx[r], f[ct][r]);
            }
        }
#pragma unroll
        for (int r = 0; r < 4; ++r) {
#pragma unroll
            for (int o = 1; o < 16; o <<= 1) mx[r] = fmaxf(mx[r], __shfl_xor(mx[r], o));
        }
#pragma unroll
        for (int ct = 0; ct < 21; ++ct) {
            if (ct <= tile) {
                const int c = ct * 16 + lrow;
#pragma unroll
                for (int r = 0; r < 4; ++r) {
                    float e = (c <= r0 + r4 + r)
                                  ? __expf((f[ct][r] - mx[r]) * 0.125f) : 0.f;
                    f[ct][r] = e;
                    sm[r] += e;
                }
            }
        }
#pragma unroll
        for (int r = 0; r < 4; ++r) {
#pragma unroll
            for (int o = 1; o < 16; o <<= 1) sm[r] += __shfl_xor(sm[r], o);
            sm[r] = 1.0f / sm[r];
        }
#pragma unroll
        for (int ct = 0; ct < 21; ++ct) {
            if (ct <= tile) {
#pragma unroll
                for (int r = 0; r < 4; ++r) f[ct][r] *= sm[r];
            }
        }

#pragma unroll
        for (int ct = 0; ct < 21; ++ct) {
            const int c = ct * 16 + lrow;
            if (c < N_TOK) {
#pragma unroll
                for (int r = 0; r < 4; ++r) {
                    const int n = r0 + r4 + r;
                    if (n < N_TOK) {
                        float v = (ct <= tile && c <= n) ? f[ct][r] : 0.f;
                        attn_out[(hb_base + n) * N_TOK + c] = v;
                    }
                }
            }
        }

        f32x4 acc[4] = {};
        bf16* pt = &ptile[w][0];
#pragma unroll
        for (int s = 0; s < 11; ++s) {
            if (s <= (tile >> 1)) {           // wave-uniform
#pragma unroll
                for (int half = 0; half < 2; ++half) {
                    const int ct2 = 2 * s + half;
                    const int c = ct2 * 16 + lrow;
#pragma unroll
                    for (int r = 0; r < 4; ++r) {
                        const int n = r0 + r4 + r;
                        float v = (ct2 <= tile && c <= n) ? f[ct2][r] : 0.f;
                        pt[(r4 + r) * 40 + half * 16 + lrow] = __float2bfloat16(v);
                    }
                }
                short8 aa = *(const short8*)&pt[lrow * 40 + lk8];
#pragma unroll
                for (int e = 0; e < 4; ++e) {
                    short8 bb = *(const short8*)&Vt[(e * 16 + lrow) * VT_LD + s * 32 + lk8];
                    acc[e] = __builtin_amdgcn_mfma_f32_16x16x32_bf16(aa, bb, acc[e], 0, 0, 0);
                }
            }
        }

#pragma unroll
        for (int e = 0; e < 4; ++e) {
#pragma unroll
            for (int r = 0; r < 4; ++r) {
                const int n = r0 + r4 + r;
                if (n < N_TOK)
                    qkv[(rowbase + n) * QKV_LD + h * 64 + e * 16 + lrow] =
                        __float2bfloat16(acc[e][r]);
            }
        }
    }
}

// ---------------------------------------------------------------------------
extern "C" void kernel_launch(void* const* d_in, const int* in_sizes, int n_in,
                              void* d_out, int out_size, void* d_ws, size_t ws_size,
                              hipStream_t stream)
{
    const void* X   = d_in[0];
    const void* STE = d_in[1];
    const void* Wq  = d_in[2];
    const void* bq  = d_in[3];
    const void* Wk  = d_in[4];
    const void* bk  = d_in[5];
    const void* Wv  = d_in[6];
    const void* bv  = d_in[7];
    const void* W1  = d_in[8];
    const void* b1  = d_in[9];
    const void* W2  = d_in[10];
    const void* b2  = d_in[11];

    float* out0     = (float*)d_out;                              // [31200][512] f32
    float* attn_out = (float*)d_out + (size_t)M_ROWS * D_MODEL;   // [64][12][325][325] f32
    bf16*  Xc       = (bf16*)attn_out;   // scratch; overwritten by attn_kernel later

    char* ws = (char*)d_ws;
    bf16*  qkv   = (bf16*)(ws);                      // 31232*1536*2 = 95,944,704
    bf16*  BtQKV = (bf16*)(ws + 95944704);           //  3,145,728
    bf16*  W1T   = (bf16*)(ws + 99090432);           //    524,288
    bf16*  W2T   = (bf16*)(ws + 99614720);           //    524,288
    float* biasQ = (float*)(ws + 100139008);         //      6,144
    float* b1f   = (float*)(ws + 100145152);         //      2,048
    float* b2f   = (float*)(ws + 100147200);         //      2,048
    int*   flag  = (int*)(ws + 100149248);           //          4
    bf16*  hbuf  = qkv + 512;                        // FFN hidden aliases k-slice

    init_flag<<<1, 64, 0, stream>>>(flag);
    detect_dtype<<<64, 256, 0, stream>>>((const unsigned short*)X, flag);

    transpose_w_tiled<<<dim3(16, 32), 256, 0, stream>>>(Wq, BtQKV, 1024, 512, flag);
    transpose_w_tiled<<<dim3(16, 32), 256, 0, stream>>>(Wk, BtQKV + 512 * 1024, 1024, 512, flag);
    transpose_w_tiled<<<dim3(16, 32), 256, 0, stream>>>(Wv, BtQKV + 1024 * 1024, 1024, 512, flag);
    transpose_w_tiled<<<dim3(16, 16), 256, 0, stream>>>(W1, W1T, 512, 512, flag);
    transpose_w_tiled<<<dim3(16, 16), 256, 0, stream>>>(W2, W2T, 512, 512, flag);
    prep_bias<<<2, 256, 0, stream>>>(bq, bk, bv, b1, b2, biasQ, b1f, b2f, flag);

    // concat(X,STE) -> bf16 Xc [31232][1024]
    concat_cast<<<(M_PAD * 128) / 256, 256, 0, stream>>>(X, STE, Xc, flag);

    // QKV projection: Xc[31232,1024] @ BtQKV^T -> qkv (+bias, relu); nby=12
    gemm_lds<0><<<244 * 12, 256, 0, stream>>>(
        Xc, 1024, BtQKV, 1024, biasQ, qkv, M_PAD, 1024, QKV_LD, 1, 12);

    // attention (ctx -> q-slice of qkv; attn -> f32 d_out region, overwrites Xc)
    attn_kernel<<<768, 512, 0, stream>>>(qkv, attn_out);

    // FFN1: relu(ctx @ W1 + b1) -> hbuf (k-slice of qkv); nby=4
    gemm_lds<0><<<244 * 4, 256, 0, stream>>>(
        qkv, QKV_LD, W1T, 512, b1f, hbuf, M_PAD, 512, QKV_LD, 1, 4);

    // FFN2: hbuf @ W2 + b2 -> out0 (f32, guarded at M_ROWS); nby=4
    gemm_lds<1><<<244 * 4, 256, 0, stream>>>(
        hbuf, QKV_LD, W2T, 512, b2f, out0, M_ROWS, 512, D_MODEL, 0, 4);
}